// Round 1
// baseline (894.408 us; speedup 1.0000x reference)
//
#include <hip/hip_runtime.h>
#include <stdint.h>

typedef unsigned short u16;
typedef unsigned int   u32;
typedef __attribute__((ext_vector_type(8))) short short8;
typedef __attribute__((ext_vector_type(4))) float f32x4;

#define NEGF (-1.0e10f)

// ---------- sizes ----------
// L=512 B=32 E=512 H2=1024 DH=1024 OUT=32000 CPY=60000
static constexpr int LL = 512, BB = 32, EE = 512, H2 = 1024, DH = 1024;
static constexpr int G4 = 4096, KX = 2560, OUTD = 32000, CPY = 60000;

// ---------- output offsets (floats) ----------
static constexpr size_t PREDS_OFF = 0;                    // 32*60000
static constexpr size_t HID_OFF   = 1920000;              // 2*32*1024
static constexpr size_t C_OFF     = HID_OFF + 65536;
static constexpr size_t ATTN_OFF  = C_OFF + 65536;        // 32*512
static constexpr size_t CS_OFF    = ATTN_OFF + 16384;     // 32*510

// ---------- workspace offsets (bytes) ----------
static constexpr size_t WS_ENC    = 0;                     // 16384*1024*2
static constexpr size_t WS_WA1T   = WS_ENC    + 33554432;  // 1024*1024*2
static constexpr size_t WS_WA2T   = WS_WA1T   + 2097152;
static constexpr size_t WS_WCT    = WS_WA2T   + 2097152;
static constexpr size_t WS_HTOPBF = WS_WCT    + 2097152;   // 32*1024*2
static constexpr size_t WS_HPF    = WS_HTOPBF + 65536;     // 32*1024*4
static constexpr size_t WS_SCORES = WS_HPF    + 131072;    // 32*512*4
static constexpr size_t WS_CSACC  = WS_SCORES + 65536;
static constexpr size_t WS_SELP   = WS_CSACC  + 65536;
static constexpr size_t WS_XT     = WS_SELP   + 65536;     // 2560*32*4
static constexpr size_t WS_CATT   = WS_XT     + 327680;
static constexpr size_t WS_HT0    = WS_CATT   + 327680;    // 1024*32*4
static constexpr size_t WS_HT1    = WS_HT0    + 131072;
static constexpr size_t WS_H0T    = WS_HT1    + 131072;
static constexpr size_t WS_GATES  = WS_H0T    + 131072;    // 4096*32*4
static constexpr size_t WS_H1     = WS_GATES  + 524288;
static constexpr size_t WS_TOTAL  = WS_H1     + 131072;

// ---------- helpers ----------
__device__ __forceinline__ u16 f2bf(float x){
  u32 u = __builtin_bit_cast(u32, x);
  u32 r = (u + 0x7FFFu + ((u >> 16) & 1u)) >> 16;
  return (u16)r;
}
__device__ __forceinline__ float bf2f(u16 h){
  u32 u = ((u32)h) << 16; return __builtin_bit_cast(float, u);
}
__device__ __forceinline__ float fsig(float x){ return 1.f/(1.f + __expf(-x)); }
__device__ __forceinline__ float ftanh(float x){
  float e = __expf(2.f*x);        // inf -> 1, 0 -> -1 : stable
  return 1.f - 2.f/(e + 1.f);
}

#define GLDS16(gp, lp) __builtin_amdgcn_global_load_lds( \
    (__attribute__((address_space(1))) void*)(gp), \
    (__attribute__((address_space(3))) void*)(lp), 16, 0, 0)

// ---------- f32 -> bf16 elementwise ----------
__global__ void k_f32_to_bf16(const float* __restrict__ in, u16* __restrict__ out, int n4){
  int stride = gridDim.x * blockDim.x;
  for (int i = blockIdx.x*blockDim.x + threadIdx.x; i < n4; i += stride){
    float4 v = ((const float4*)in)[i];
    u32 lo = (u32)f2bf(v.x) | ((u32)f2bf(v.y) << 16);
    u32 hi = (u32)f2bf(v.z) | ((u32)f2bf(v.w) << 16);
    ((uint2*)out)[i] = make_uint2(lo, hi);
  }
}

// ---------- transpose W_attn (2048k x 1024n) -> Wa1T/Wa2T [n][k] bf16 ----------
__global__ void k_wattn_t(const float* __restrict__ W, u16* __restrict__ wa1t, u16* __restrict__ wa2t){
  __shared__ float Tt[64*65];
  int n0 = blockIdx.x*64, k0 = blockIdx.y*64;
  int t = threadIdx.x;
  int nn = t & 63, kq = t >> 6;
  for (int kk = kq; kk < 64; kk += 4)
    Tt[kk*65 + nn] = W[(size_t)(k0+kk)*1024 + n0 + nn];
  __syncthreads();
  u16* dst = (k0 < 1024) ? wa1t : wa2t;
  int kbase = (k0 < 1024) ? k0 : (k0 - 1024);
  int kk2 = t & 63, nq = t >> 6;
  for (int nn2 = nq; nn2 < 64; nn2 += 4)
    dst[(size_t)(n0+nn2)*1024 + kbase + kk2] = f2bf(Tt[kk2*65 + nn2]);
}

// ---------- prep: embedded, hT, htop bf16, zero accum, sel softmax ----------
__global__ void k_prep(const int* __restrict__ src, const int* __restrict__ inp,
                       const float* __restrict__ hidden, const float* __restrict__ selw,
                       const int* __restrict__ s2c, const float* __restrict__ emb,
                       const int* __restrict__ mask,
                       float* __restrict__ xT, float* __restrict__ catT,
                       float* __restrict__ hT0, float* __restrict__ hT1,
                       u16* __restrict__ htopbf, float* __restrict__ scores,
                       float* __restrict__ csacc, float* __restrict__ selp)
{
  int b = blockIdx.x, t = threadIdx.x;
  int ib = inp[b];
  for (int h = t; h < 512; h += 256){
    float e = emb[(size_t)ib*512 + h];
    xT[h*32 + b] = e;
    catT[(2048 + h)*32 + b] = e;
  }
  for (int k = t; k < 1024; k += 256){
    float h0v = hidden[b*1024 + k];
    float h1v = hidden[32768 + b*1024 + k];
    hT0[k*32 + b] = h0v;
    hT1[k*32 + b] = h1v;
    htopbf[b*1024 + k] = f2bf(h1v);
  }
  for (int l = t; l < 512; l += 256){
    scores[b*512 + l] = 0.f;
    csacc[b*512 + l] = 0.f;
  }
  __shared__ float red[256];
  float lg[2];
  #pragma unroll
  for (int i = 0; i < 2; ++i){
    int j = t + i*256;
    lg[i] = NEGF;
    if (j < 510){
      int cs = s2c[src[(j+1)*32 + b]];
      if (cs == ib) lg[i] = selw[b*510 + j];
    }
  }
  red[t] = fmaxf(lg[0], lg[1]); __syncthreads();
  for (int s = 128; s > 0; s >>= 1){ if (t < s) red[t] = fmaxf(red[t], red[t+s]); __syncthreads(); }
  float mx = red[0]; __syncthreads();
  float e0 = (t < 510)     ? __expf(lg[0] - mx) : 0.f;
  float e1 = (t+256 < 510) ? __expf(lg[1] - mx) : 0.f;
  red[t] = e0 + e1; __syncthreads();
  for (int s = 128; s > 0; s >>= 1){ if (t < s) red[t] += red[t+s]; __syncthreads(); }
  float inv = 1.f / red[0];
  #pragma unroll
  for (int i = 0; i < 2; ++i){
    int j = t + i*256;
    if (j < 510){
      float v = ((i == 0) ? e0 : e1) * inv;
      int l = j + 1;
      selp[b*512 + l] = (mask[b*512 + l] != 0) ? v : NEGF;
    }
  }
}

// ---------- unified bf16 MFMA GEMM (128x128 tile, BK=64, xor-swizzled LDS) ----------
// C = A(MxK) * B^T(N rows x K)  ; epilogue either
//   store:  out[row*NT*128+n] = acc + preadd[(row&31)*spa + n]
//   dot  :  part = sum_n tanh(acc + preadd[(row&31)*spa+n]) * dotw[(row&31)*sdw+n]
//           atomicAdd(dotout[(row&31)*Ldot + row>>5], part)
__launch_bounds__(256)
__global__ void k_mfma(const u16* __restrict__ A, int lda, int Mvalid,
                       const u16* __restrict__ Bmat, int ldb, int K,
                       const float* __restrict__ preadd, int spa,
                       const float* __restrict__ dotw, int sdw,
                       float* __restrict__ dotout, int Ldot, int skipedge,
                       float* __restrict__ outstore, int NT)
{
  __shared__ u16 As[128*64];
  __shared__ u16 Bs[128*64];
  int nwg = gridDim.x, bid = blockIdx.x;
  int q = nwg >> 3, r = nwg & 7, xc = bid & 7, ix = bid >> 3;
  int wg = (xc < r ? xc*(q+1) : r*(q+1) + (xc - r)*q) + ix;   // bijective XCD swizzle
  int mt = wg / NT, nt = wg % NT;
  int m0 = mt * 128, n0 = nt * 128;
  int tid = threadIdx.x, lane = tid & 63, wid = tid >> 6;
  int wm = wid >> 1, wn = wid & 1;

  f32x4 acc[4][4];
  #pragma unroll
  for (int i = 0; i < 4; ++i)
    #pragma unroll
    for (int j = 0; j < 4; ++j)
      acc[i][j] = (f32x4){0.f, 0.f, 0.f, 0.f};

  int srow = lane >> 3;                 // row within 8-row staging group
  int soff = ((lane & 7) ^ srow) * 8;   // pre-swizzled source chunk (elements)

  for (int k0 = 0; k0 < K; k0 += 64){
    __syncthreads();
    #pragma unroll
    for (int j = 0; j < 4; ++j){
      int qq = wid*4 + j;
      int ra = m0 + qq*8 + srow; if (ra >= Mvalid) ra = Mvalid - 1;
      GLDS16(A + (size_t)ra*lda + k0 + soff, (char*)As + qq*1024 + lane*16);
      int rb = n0 + qq*8 + srow;
      GLDS16(Bmat + (size_t)rb*ldb + k0 + soff, (char*)Bs + qq*1024 + lane*16);
    }
    __syncthreads();
    #pragma unroll
    for (int kk = 0; kk < 2; ++kk){
      short8 af[4], bfr[4];
      #pragma unroll
      for (int mi = 0; mi < 4; ++mi){
        int rr = wm*64 + mi*16 + (lane & 15);
        int kb = (kk*64 + ((lane >> 4) << 4)) ^ ((rr & 7) << 4);
        af[mi] = *(const short8*)((const char*)As + rr*128 + kb);
      }
      #pragma unroll
      for (int nj = 0; nj < 4; ++nj){
        int rr = wn*64 + nj*16 + (lane & 15);
        int kb = (kk*64 + ((lane >> 4) << 4)) ^ ((rr & 7) << 4);
        bfr[nj] = *(const short8*)((const char*)Bs + rr*128 + kb);
      }
      #pragma unroll
      for (int mi = 0; mi < 4; ++mi)
        #pragma unroll
        for (int nj = 0; nj < 4; ++nj)
          acc[mi][nj] = __builtin_amdgcn_mfma_f32_16x16x32_bf16(af[mi], bfr[nj], acc[mi][nj], 0, 0, 0);
    }
  }

  int g = lane >> 4, cn = lane & 15;
  if (outstore){
    int Nld = NT * 128;
    #pragma unroll
    for (int mi = 0; mi < 4; ++mi)
      #pragma unroll
      for (int rr2 = 0; rr2 < 4; ++rr2){
        int row = m0 + wm*64 + mi*16 + g*4 + rr2;
        if (row < Mvalid){
          #pragma unroll
          for (int nj = 0; nj < 4; ++nj){
            int n = n0 + wn*64 + nj*16 + cn;
            outstore[(size_t)row*Nld + n] = acc[mi][nj][rr2] + preadd[(size_t)(row & 31)*spa + n];
          }
        }
      }
  } else {
    #pragma unroll
    for (int mi = 0; mi < 4; ++mi)
      #pragma unroll
      for (int rr2 = 0; rr2 < 4; ++rr2){
        int row = m0 + wm*64 + mi*16 + g*4 + rr2;
        int bb = row & 31;
        float part = 0.f;
        #pragma unroll
        for (int nj = 0; nj < 4; ++nj){
          int n = n0 + wn*64 + nj*16 + cn;
          float tv = ftanh(acc[mi][nj][rr2] + preadd[(size_t)bb*spa + n]);
          part = fmaf(tv, dotw[(size_t)bb*sdw + n], part);
        }
        part += __shfl_xor(part, 1);
        part += __shfl_xor(part, 2);
        part += __shfl_xor(part, 4);
        part += __shfl_xor(part, 8);
        if (cn == 0){
          int l = row >> 5;
          if (!skipedge || (l > 0 && l < Ldot - 1))
            atomicAdd(&dotout[(size_t)bb*Ldot + l], part);
        }
      }
  }
}

// ---------- attention softmax over L per b ----------
__global__ void k_softmax_attn(const float* __restrict__ scores, const int* __restrict__ mask,
                               float* __restrict__ attnw){
  int b = blockIdx.x, t = threadIdx.x;
  __shared__ float red[256];
  float v0 = scores[b*512 + t];
  float v1 = scores[b*512 + 256 + t];
  if (mask[b*512 + t] == 0) v0 = NEGF;
  if (mask[b*512 + 256 + t] == 0) v1 = NEGF;
  red[t] = fmaxf(v0, v1); __syncthreads();
  for (int s = 128; s > 0; s >>= 1){ if (t < s) red[t] = fmaxf(red[t], red[t+s]); __syncthreads(); }
  float mx = red[0]; __syncthreads();
  float e0 = __expf(v0 - mx), e1 = __expf(v1 - mx);
  red[t] = e0 + e1; __syncthreads();
  for (int s = 128; s > 0; s >>= 1){ if (t < s) red[t] += red[t+s]; __syncthreads(); }
  float inv = 1.f / red[0];
  attnw[b*512 + t] = e0 * inv;
  attnw[b*512 + 256 + t] = e1 * inv;
}

// ---------- attentive & selective reads ----------
__global__ void k_reads(const u16* __restrict__ encbf, const float* __restrict__ attnw,
                        const float* __restrict__ selp,
                        float* __restrict__ xT, float* __restrict__ catT){
  int b = blockIdx.y;
  int h = blockIdx.x*128 + threadIdx.x;
  float aa = 0.f, as = 0.f;
  #pragma unroll 4
  for (int l = 0; l < 512; ++l){
    float e = bf2f(encbf[((size_t)l*32 + b)*1024 + h]);
    aa = fmaf(attnw[b*512 + l], e, aa);
    if (l >= 1 && l < 511) as = fmaf(selp[b*512 + l], e, as);
  }
  xT[(512 + h)*32 + b]   = aa;
  catT[(1024 + h)*32 + b] = aa;
  xT[(1536 + h)*32 + b]  = as;
}

// ---------- batch-32 vector GEMV: out[o][b] (or transposed-to-row store) ----------
template<int ROWS>
__device__ __forceinline__ void gemv_pair(const float* __restrict__ W, const float* __restrict__ xT,
                                          int K, int o0, int b, int h, float* acc){
  for (int kc = 0; kc < K; kc += 64){
    float xr[32];
    const float* xp = xT + (size_t)(kc + h*32)*32 + b;
    #pragma unroll
    for (int j = 0; j < 32; ++j) xr[j] = xp[j*32];
    #pragma unroll
    for (int o = 0; o < ROWS; ++o){
      const float4* wp = (const float4*)(W + (size_t)(o0 + o)*K + kc + h*32);
      #pragma unroll
      for (int j4 = 0; j4 < 8; ++j4){
        float4 wv = wp[j4];
        acc[o] = fmaf(wv.x, xr[j4*4+0], acc[o]);
        acc[o] = fmaf(wv.y, xr[j4*4+1], acc[o]);
        acc[o] = fmaf(wv.z, xr[j4*4+2], acc[o]);
        acc[o] = fmaf(wv.w, xr[j4*4+3], acc[o]);
      }
    }
  }
}

template<int ROWS, bool TMODE>
__launch_bounds__(256)
__global__ void k_gemv32(const float* __restrict__ W1, const float* __restrict__ x1T, int K1,
                         const float* __restrict__ W2, const float* __restrict__ x2T, int K2,
                         const float* __restrict__ bias1, const float* __restrict__ bias2,
                         float* __restrict__ outT, float* __restrict__ outB, size_t ldo)
{
  int tid = threadIdx.x, lane = tid & 63, w = tid >> 6;
  int b = lane & 31, h = lane >> 5;
  int o0 = blockIdx.x*(ROWS*4) + w*ROWS;
  float acc[ROWS];
  #pragma unroll
  for (int o = 0; o < ROWS; ++o) acc[o] = 0.f;
  gemv_pair<ROWS>(W1, x1T, K1, o0, b, h, acc);
  if (W2) gemv_pair<ROWS>(W2, x2T, K2, o0, b, h, acc);
  #pragma unroll
  for (int o = 0; o < ROWS; ++o) acc[o] += __shfl_xor(acc[o], 32);

  if constexpr (!TMODE){
    if (h == 0){
      #pragma unroll
      for (int o = 0; o < ROWS; ++o){
        float v = acc[o];
        if (bias1) v += bias1[o0 + o];
        if (bias2) v += bias2[o0 + o];
        outT[(size_t)(o0 + o)*32 + b] = v;
      }
    }
  } else {
    __shared__ float ts[ROWS*4*33];
    if (h == 0){
      #pragma unroll
      for (int o = 0; o < ROWS; ++o){
        float v = acc[o];
        if (bias1) v += bias1[o0 + o];
        ts[(w*ROWS + o)*33 + b] = v;
      }
    }
    __syncthreads();
    constexpr int RB = ROWS*4;
    #pragma unroll
    for (int bb = 0; bb < 8; ++bb){
      int b2 = w*8 + bb;
      if (lane < RB)
        outB[(size_t)b2*ldo + blockIdx.x*RB + lane] = ts[lane*33 + b2];
    }
  }
}

// ---------- LSTM cell ----------
__global__ void k_cell(const float* __restrict__ gT, const float* __restrict__ c_in,
                       float* __restrict__ h_out, float* __restrict__ c_out,
                       float* __restrict__ hT_next, float* __restrict__ h_plain){
  int idx = blockIdx.x*256 + threadIdx.x;
  int b = idx >> 10, j = idx & 1023;
  float gi = gT[j*32 + b];
  float gf = gT[(1024 + j)*32 + b];
  float gg = gT[(2048 + j)*32 + b];
  float go = gT[(3072 + j)*32 + b];
  float cv = c_in[b*1024 + j];
  float cnv = fsig(gf)*cv + fsig(gi)*ftanh(gg);
  float hn  = fsig(go)*ftanh(cnv);
  c_out[b*1024 + j] = cnv;
  h_out[b*1024 + j] = hn;
  if (hT_next) hT_next[j*32 + b] = hn;
  if (h_plain) h_plain[b*1024 + j] = hn;
}

// ---------- preds tail zero ----------
__global__ void k_zerotail(float* __restrict__ preds){
  int i = blockIdx.x*256 + threadIdx.x;          // 32 * 7000 float4
  if (i < 224000){
    int b = i / 7000, t = i % 7000;
    ((float4*)(preds + (size_t)b*CPY + OUTD))[t] = make_float4(0.f, 0.f, 0.f, 0.f);
  }
}

// ---------- copy-scores finalize ----------
__global__ void k_csfinal(const float* __restrict__ csacc, const int* __restrict__ mask,
                          float* __restrict__ cs_out){
  int i = blockIdx.x*256 + threadIdx.x;
  if (i < 16320){
    int b = i / 510, j = i % 510, l = j + 1;
    cs_out[b*510 + j] = (mask[b*512 + l] != 0) ? csacc[b*512 + l] : NEGF;
  }
}

// ---------- serial scatter (numpy last-wins semantics) ----------
__global__ void k_scatter(const int* __restrict__ src, const int* __restrict__ s2c,
                          const float* __restrict__ cs_out, float* __restrict__ preds){
  int b = threadIdx.x;
  if (b < 32){
    for (int j = 0; j < 510; ++j){
      int idx = s2c[src[(j+1)*32 + b]];
      preds[(size_t)b*CPY + idx] = cs_out[b*510 + j];
    }
  }
}

extern "C" void kernel_launch(void* const* d_in, const int* in_sizes, int n_in,
                              void* d_out, int out_size, void* d_ws, size_t ws_size,
                              hipStream_t stream){
  const int*   src    = (const int*)  d_in[0];
  const int*   inp    = (const int*)  d_in[1];
  const float* hidden = (const float*)d_in[2];
  const float* cst    = (const float*)d_in[3];
  const float* enc    = (const float*)d_in[4];
  const int*   mask   = (const int*)  d_in[5];
  const float* selw   = (const float*)d_in[6];
  const int*   s2c    = (const int*)  d_in[7];
  const float* emb    = (const float*)d_in[8];
  const float* W_attn = (const float*)d_in[9];
  const float* b_attn = (const float*)d_in[10];
  const float* v_attn = (const float*)d_in[11];
  const float* W_ih0  = (const float*)d_in[12];
  const float* W_hh0  = (const float*)d_in[13];
  const float* b_ih0  = (const float*)d_in[14];
  const float* b_hh0  = (const float*)d_in[15];
  const float* W_ih1  = (const float*)d_in[16];
  const float* W_hh1  = (const float*)d_in[17];
  const float* b_ih1  = (const float*)d_in[18];
  const float* b_hh1  = (const float*)d_in[19];
  const float* W_fc   = (const float*)d_in[20];
  const float* b_fc   = (const float*)d_in[21];
  const float* W_copy = (const float*)d_in[22];
  const float* b_copy = (const float*)d_in[23];

  if (ws_size < WS_TOTAL) return;   // would corrupt; fail visibly instead

  float* out = (float*)d_out;
  char*  ws  = (char*)d_ws;
  u16*   encbf  = (u16*)  (ws + WS_ENC);
  u16*   wa1t   = (u16*)  (ws + WS_WA1T);
  u16*   wa2t   = (u16*)  (ws + WS_WA2T);
  u16*   wct    = (u16*)  (ws + WS_WCT);
  u16*   htopbf = (u16*)  (ws + WS_HTOPBF);
  float* hpf    = (float*)(ws + WS_HPF);
  float* scores = (float*)(ws + WS_SCORES);
  float* csacc  = (float*)(ws + WS_CSACC);
  float* selp   = (float*)(ws + WS_SELP);
  float* xT     = (float*)(ws + WS_XT);
  float* catT   = (float*)(ws + WS_CATT);
  float* hT0    = (float*)(ws + WS_HT0);
  float* hT1    = (float*)(ws + WS_HT1);
  float* h0T    = (float*)(ws + WS_H0T);
  float* gates  = (float*)(ws + WS_GATES);
  float* h1     = (float*)(ws + WS_H1);

  // converts / transposes
  k_f32_to_bf16<<<2048, 256, 0, stream>>>(enc,    encbf, (LL*BB*H2)/4);
  k_f32_to_bf16<<<512,  256, 0, stream>>>(W_copy, wct,   (DH*H2)/4);
  k_wattn_t<<<dim3(16, 32), 256, 0, stream>>>(W_attn, wa1t, wa2t);
  k_prep<<<32, 256, 0, stream>>>(src, inp, hidden, selw, s2c, emb, mask,
                                 xT, catT, hT0, hT1, htopbf, scores, csacc, selp);

  // h-part: hpf[b][n] = b_attn[n] + h_top @ Wa1
  k_mfma<<<8, 256, 0, stream>>>(htopbf, 1024, 32, wa1t, 1024, 1024,
                                b_attn, 0, nullptr, 0, nullptr, 512, 0, hpf, 8);
  // attention scores: atomicAdd sum_n tanh(enc@Wa2 + hpf) * v_attn
  k_mfma<<<1024, 256, 0, stream>>>(encbf, 1024, LL*BB, wa2t, 1024, 1024,
                                   hpf, 1024, v_attn, 0, scores, 512, 0, nullptr, 8);
  k_softmax_attn<<<32, 256, 0, stream>>>(scores, mask, out + ATTN_OFF);
  k_reads<<<dim3(8, 32), 128, 0, stream>>>(encbf, out + ATTN_OFF, selp, xT, catT);

  // LSTM layer 0
  k_gemv32<4, false><<<256, 256, 0, stream>>>(W_ih0, xT, KX, W_hh0, hT0, DH,
                                              b_ih0, b_hh0, gates, nullptr, 0);
  k_cell<<<128, 256, 0, stream>>>(gates, cst, out + HID_OFF, out + C_OFF, h0T, nullptr);
  // LSTM layer 1
  k_gemv32<4, false><<<256, 256, 0, stream>>>(W_ih1, h0T, DH, W_hh1, hT1, DH,
                                              b_ih1, b_hh1, gates, nullptr, 0);
  k_cell<<<128, 256, 0, stream>>>(gates, cst + 32768, out + HID_OFF + 32768,
                                  out + C_OFF + 32768, catT, h1);

  // copy scores: atomicAdd sum_n tanh(enc@W_copy^T + b_copy) * h1 (skip l=0, l=511)
  k_mfma<<<1024, 256, 0, stream>>>(encbf, 1024, LL*BB, wct, 1024, 1024,
                                   b_copy, 0, h1, 1024, csacc, 512, 1, nullptr, 8);

  // generator -> preds[:, :32000]
  k_gemv32<8, true><<<1000, 256, 0, stream>>>(W_fc, catT, KX, nullptr, nullptr, 0,
                                              b_fc, nullptr, nullptr, out, (size_t)CPY);
  k_zerotail<<<875, 256, 0, stream>>>(out);
  k_csfinal<<<64, 256, 0, stream>>>(csacc, mask, out + CS_OFF);
  k_scatter<<<1, 64, 0, stream>>>(src, s2c, out + CS_OFF, out);
}

// Round 2
// 626.135 us; speedup vs baseline: 1.4285x; 1.4285x over previous
//
#include <hip/hip_runtime.h>
#include <stdint.h>

typedef unsigned short u16;
typedef unsigned int   u32;
typedef __attribute__((ext_vector_type(8))) short short8;
typedef __attribute__((ext_vector_type(4))) float f32x4;

#define NEGF (-1.0e10f)

// ---------- sizes ----------
static constexpr int LL = 512, BB = 32, EE = 512, H2 = 1024, DH = 1024;
static constexpr int G4 = 4096, KX = 2560, OUTD = 32000, CPY = 60000;

// ---------- output offsets (floats) ----------
static constexpr size_t PREDS_OFF = 0;                    // 32*60000
static constexpr size_t HID_OFF   = 1920000;              // 2*32*1024
static constexpr size_t C_OFF     = HID_OFF + 65536;
static constexpr size_t ATTN_OFF  = C_OFF + 65536;        // 32*512
static constexpr size_t CS_OFF    = ATTN_OFF + 16384;     // 32*510

// ---------- workspace offsets (bytes) ----------
static constexpr size_t WS_ENC    = 0;                     // 16384*1024*2
static constexpr size_t WS_WA1T   = WS_ENC    + 33554432;  // 1024*1024*2
static constexpr size_t WS_WA2T   = WS_WA1T   + 2097152;
static constexpr size_t WS_WCT    = WS_WA2T   + 2097152;
static constexpr size_t WS_HTOPBF = WS_WCT    + 2097152;   // 32*1024*2
static constexpr size_t WS_HPF    = WS_HTOPBF + 65536;     // 32*1024*4
static constexpr size_t WS_SCORES = WS_HPF    + 131072;    // 32*512*4
static constexpr size_t WS_CSACC  = WS_SCORES + 65536;
static constexpr size_t WS_SELP   = WS_CSACC  + 65536;
static constexpr size_t WS_XT     = WS_SELP   + 65536;     // 2560*32*4
static constexpr size_t WS_CATT   = WS_XT     + 327680;
static constexpr size_t WS_HT0    = WS_CATT   + 327680;    // 1024*32*4
static constexpr size_t WS_HT1    = WS_HT0    + 131072;
static constexpr size_t WS_H0T    = WS_HT1    + 131072;
static constexpr size_t WS_GATES  = WS_H0T    + 131072;    // 4096*32*4
static constexpr size_t WS_H1     = WS_GATES  + 524288;
static constexpr size_t WS_TOTAL  = WS_H1     + 131072;

// ---------- helpers ----------
__device__ __forceinline__ u16 f2bf(float x){
  u32 u = __builtin_bit_cast(u32, x);
  u32 r = (u + 0x7FFFu + ((u >> 16) & 1u)) >> 16;
  return (u16)r;
}
__device__ __forceinline__ float bf2f(u16 h){
  u32 u = ((u32)h) << 16; return __builtin_bit_cast(float, u);
}
__device__ __forceinline__ float fsig(float x){ return 1.f/(1.f + __expf(-x)); }
__device__ __forceinline__ float ftanh(float x){
  float e = __expf(2.f*x);        // inf -> 1, 0 -> -1 : stable
  return 1.f - 2.f/(e + 1.f);
}

#define GLDS16(gp, lp) __builtin_amdgcn_global_load_lds( \
    (__attribute__((address_space(1))) void*)(gp), \
    (__attribute__((address_space(3))) void*)(lp), 16, 0, 0)

// ---------- f32 -> bf16 elementwise ----------
__global__ void k_f32_to_bf16(const float* __restrict__ in, u16* __restrict__ out, int n4){
  int stride = gridDim.x * blockDim.x;
  for (int i = blockIdx.x*blockDim.x + threadIdx.x; i < n4; i += stride){
    float4 v = ((const float4*)in)[i];
    u32 lo = (u32)f2bf(v.x) | ((u32)f2bf(v.y) << 16);
    u32 hi = (u32)f2bf(v.z) | ((u32)f2bf(v.w) << 16);
    ((uint2*)out)[i] = make_uint2(lo, hi);
  }
}

// ---------- transpose W_attn (2048k x 1024n) -> Wa1T/Wa2T [n][k] bf16 ----------
__global__ void k_wattn_t(const float* __restrict__ W, u16* __restrict__ wa1t, u16* __restrict__ wa2t){
  __shared__ float Tt[64*65];
  int n0 = blockIdx.x*64, k0 = blockIdx.y*64;
  int t = threadIdx.x;
  int nn = t & 63, kq = t >> 6;
  for (int kk = kq; kk < 64; kk += 4)
    Tt[kk*65 + nn] = W[(size_t)(k0+kk)*1024 + n0 + nn];
  __syncthreads();
  u16* dst = (k0 < 1024) ? wa1t : wa2t;
  int kbase = (k0 < 1024) ? k0 : (k0 - 1024);
  int kk2 = t & 63, nq = t >> 6;
  for (int nn2 = nq; nn2 < 64; nn2 += 4)
    dst[(size_t)(n0+nn2)*1024 + kbase + kk2] = f2bf(Tt[kk2*65 + nn2]);
}

// ---------- prep: embedded, hT, htop bf16, zero accum, sel softmax ----------
__global__ void k_prep(const int* __restrict__ src, const int* __restrict__ inp,
                       const float* __restrict__ hidden, const float* __restrict__ selw,
                       const int* __restrict__ s2c, const float* __restrict__ emb,
                       const int* __restrict__ mask,
                       float* __restrict__ xT, float* __restrict__ catT,
                       float* __restrict__ hT0, float* __restrict__ hT1,
                       u16* __restrict__ htopbf, float* __restrict__ scores,
                       float* __restrict__ csacc, float* __restrict__ selp)
{
  int b = blockIdx.x, t = threadIdx.x;
  int ib = inp[b];
  for (int h = t; h < 512; h += 256){
    float e = emb[(size_t)ib*512 + h];
    xT[h*32 + b] = e;
    catT[(2048 + h)*32 + b] = e;
  }
  for (int k = t; k < 1024; k += 256){
    float h0v = hidden[b*1024 + k];
    float h1v = hidden[32768 + b*1024 + k];
    hT0[k*32 + b] = h0v;
    hT1[k*32 + b] = h1v;
    htopbf[b*1024 + k] = f2bf(h1v);
  }
  for (int l = t; l < 512; l += 256){
    scores[b*512 + l] = 0.f;
    csacc[b*512 + l] = 0.f;
  }
  __shared__ float red[256];
  float lg[2];
  #pragma unroll
  for (int i = 0; i < 2; ++i){
    int j = t + i*256;
    lg[i] = NEGF;
    if (j < 510){
      int cs = s2c[src[(j+1)*32 + b]];
      if (cs == ib) lg[i] = selw[b*510 + j];
    }
  }
  red[t] = fmaxf(lg[0], lg[1]); __syncthreads();
  for (int s = 128; s > 0; s >>= 1){ if (t < s) red[t] = fmaxf(red[t], red[t+s]); __syncthreads(); }
  float mx = red[0]; __syncthreads();
  float e0 = (t < 510)     ? __expf(lg[0] - mx) : 0.f;
  float e1 = (t+256 < 510) ? __expf(lg[1] - mx) : 0.f;
  red[t] = e0 + e1; __syncthreads();
  for (int s = 128; s > 0; s >>= 1){ if (t < s) red[t] += red[t+s]; __syncthreads(); }
  float inv = 1.f / red[0];
  #pragma unroll
  for (int i = 0; i < 2; ++i){
    int j = t + i*256;
    if (j < 510){
      float v = ((i == 0) ? e0 : e1) * inv;
      int l = j + 1;
      selp[b*512 + l] = (mask[b*512 + l] != 0) ? v : NEGF;
    }
  }
}

// ---------- unified bf16 MFMA GEMM (128x128 tile, BK=64, xor-swizzled LDS) ----------
__launch_bounds__(256)
__global__ void k_mfma(const u16* __restrict__ A, int lda, int Mvalid,
                       const u16* __restrict__ Bmat, int ldb, int K,
                       const float* __restrict__ preadd, int spa,
                       const float* __restrict__ dotw, int sdw,
                       float* __restrict__ dotout, int Ldot, int skipedge,
                       float* __restrict__ outstore, int NT)
{
  __shared__ u16 As[128*64];
  __shared__ u16 Bs[128*64];
  int nwg = gridDim.x, bid = blockIdx.x;
  int q = nwg >> 3, r = nwg & 7, xc = bid & 7, ix = bid >> 3;
  int wg = (xc < r ? xc*(q+1) : r*(q+1) + (xc - r)*q) + ix;   // bijective XCD swizzle
  int mt = wg / NT, nt = wg % NT;
  int m0 = mt * 128, n0 = nt * 128;
  int tid = threadIdx.x, lane = tid & 63, wid = tid >> 6;
  int wm = wid >> 1, wn = wid & 1;

  f32x4 acc[4][4];
  #pragma unroll
  for (int i = 0; i < 4; ++i)
    #pragma unroll
    for (int j = 0; j < 4; ++j)
      acc[i][j] = (f32x4){0.f, 0.f, 0.f, 0.f};

  int srow = lane >> 3;                 // row within 8-row staging group
  int soff = ((lane & 7) ^ srow) * 8;   // pre-swizzled source chunk (elements)

  for (int k0 = 0; k0 < K; k0 += 64){
    __syncthreads();
    #pragma unroll
    for (int j = 0; j < 4; ++j){
      int qq = wid*4 + j;
      int ra = m0 + qq*8 + srow; if (ra >= Mvalid) ra = Mvalid - 1;
      GLDS16(A + (size_t)ra*lda + k0 + soff, (char*)As + qq*1024 + lane*16);
      int rb = n0 + qq*8 + srow;
      GLDS16(Bmat + (size_t)rb*ldb + k0 + soff, (char*)Bs + qq*1024 + lane*16);
    }
    __syncthreads();
    #pragma unroll
    for (int kk = 0; kk < 2; ++kk){
      short8 af[4], bfr[4];
      #pragma unroll
      for (int mi = 0; mi < 4; ++mi){
        int rr = wm*64 + mi*16 + (lane & 15);
        int kb = (kk*64 + ((lane >> 4) << 4)) ^ ((rr & 7) << 4);
        af[mi] = *(const short8*)((const char*)As + rr*128 + kb);
      }
      #pragma unroll
      for (int nj = 0; nj < 4; ++nj){
        int rr = wn*64 + nj*16 + (lane & 15);
        int kb = (kk*64 + ((lane >> 4) << 4)) ^ ((rr & 7) << 4);
        bfr[nj] = *(const short8*)((const char*)Bs + rr*128 + kb);
      }
      #pragma unroll
      for (int mi = 0; mi < 4; ++mi)
        #pragma unroll
        for (int nj = 0; nj < 4; ++nj)
          acc[mi][nj] = __builtin_amdgcn_mfma_f32_16x16x32_bf16(af[mi], bfr[nj], acc[mi][nj], 0, 0, 0);
    }
  }

  int g = lane >> 4, cn = lane & 15;
  if (outstore){
    int Nld = NT * 128;
    #pragma unroll
    for (int mi = 0; mi < 4; ++mi)
      #pragma unroll
      for (int rr2 = 0; rr2 < 4; ++rr2){
        int row = m0 + wm*64 + mi*16 + g*4 + rr2;
        if (row < Mvalid){
          #pragma unroll
          for (int nj = 0; nj < 4; ++nj){
            int n = n0 + wn*64 + nj*16 + cn;
            outstore[(size_t)row*Nld + n] = acc[mi][nj][rr2] + preadd[(size_t)(row & 31)*spa + n];
          }
        }
      }
  } else {
    #pragma unroll
    for (int mi = 0; mi < 4; ++mi)
      #pragma unroll
      for (int rr2 = 0; rr2 < 4; ++rr2){
        int row = m0 + wm*64 + mi*16 + g*4 + rr2;
        int bb = row & 31;
        float part = 0.f;
        #pragma unroll
        for (int nj = 0; nj < 4; ++nj){
          int n = n0 + wn*64 + nj*16 + cn;
          float tv = ftanh(acc[mi][nj][rr2] + preadd[(size_t)bb*spa + n]);
          part = fmaf(tv, dotw[(size_t)bb*sdw + n], part);
        }
        part += __shfl_xor(part, 1);
        part += __shfl_xor(part, 2);
        part += __shfl_xor(part, 4);
        part += __shfl_xor(part, 8);
        if (cn == 0){
          int l = row >> 5;
          if (!skipedge || (l > 0 && l < Ldot - 1))
            atomicAdd(&dotout[(size_t)bb*Ldot + l], part);
        }
      }
  }
}

// ---------- attention softmax over L per b ----------
__global__ void k_softmax_attn(const float* __restrict__ scores, const int* __restrict__ mask,
                               float* __restrict__ attnw){
  int b = blockIdx.x, t = threadIdx.x;
  __shared__ float red[256];
  float v0 = scores[b*512 + t];
  float v1 = scores[b*512 + 256 + t];
  if (mask[b*512 + t] == 0) v0 = NEGF;
  if (mask[b*512 + 256 + t] == 0) v1 = NEGF;
  red[t] = fmaxf(v0, v1); __syncthreads();
  for (int s = 128; s > 0; s >>= 1){ if (t < s) red[t] = fmaxf(red[t], red[t+s]); __syncthreads(); }
  float mx = red[0]; __syncthreads();
  float e0 = __expf(v0 - mx), e1 = __expf(v1 - mx);
  red[t] = e0 + e1; __syncthreads();
  for (int s = 128; s > 0; s >>= 1){ if (t < s) red[t] += red[t+s]; __syncthreads(); }
  float inv = 1.f / red[0];
  attnw[b*512 + t] = e0 * inv;
  attnw[b*512 + 256 + t] = e1 * inv;
}

// ---------- attentive & selective reads ----------
__global__ void k_reads(const u16* __restrict__ encbf, const float* __restrict__ attnw,
                        const float* __restrict__ selp,
                        float* __restrict__ xT, float* __restrict__ catT){
  int b = blockIdx.y;
  int h = blockIdx.x*128 + threadIdx.x;
  float aa = 0.f, as = 0.f;
  #pragma unroll 4
  for (int l = 0; l < 512; ++l){
    float e = bf2f(encbf[((size_t)l*32 + b)*1024 + h]);
    aa = fmaf(attnw[b*512 + l], e, aa);
    if (l >= 1 && l < 511) as = fmaf(selp[b*512 + l], e, as);
  }
  xT[(512 + h)*32 + b]   = aa;
  catT[(1024 + h)*32 + b] = aa;
  xT[(1536 + h)*32 + b]  = as;
}

// ---------- LDS-staged fp32 GEMV, batch 32 ----------
// out[o][b] = bias(o) + sum_k W1[o][k] x1T[k][b] (+ W2/x2T pair)
// Block: RB rows, 256 threads. W chunk [RB][128] fp32 staged to LDS via
// global_load_lds (coalesced 1KB/wave-instr), double-buffered. Each of the
// 8 (wave, half) groups owns a 16-wide k-slice; x in registers; W broadcast
// ds_read_b128 (uniform addr per half-wave = conflict-free). LDS reduce at end.
template<int RB, bool TMODE>
__launch_bounds__(256)
__global__ void k_wstream(const float* __restrict__ W1, const float* __restrict__ x1T, int K1,
                          const float* __restrict__ W2, const float* __restrict__ x2T, int K2,
                          const float* __restrict__ bias1, const float* __restrict__ bias2,
                          float* __restrict__ outT, float* __restrict__ outB, size_t ldo)
{
  __shared__ float Ws[2][RB*128];
  const int tid = threadIdx.x;
  const int lane = tid & 63, w = tid >> 6;
  const int b = lane & 31, g = lane >> 5;
  const int ksub = (w*2 + g)*16;          // k-offset within 128-chunk
  const int o0 = blockIdx.x * RB;

  const int c1 = K1 >> 7;
  const int c2 = K2 >> 7;
  const int total = c1 + c2;

  float acc[RB];
  #pragma unroll
  for (int r = 0; r < RB; ++r) acc[r] = 0.f;

  auto stage = [&](int c, float* buf){
    const float* Wp = (c < c1) ? W1 : W2;
    int K  = (c < c1) ? K1 : K2;
    int kc = ((c < c1) ? c : (c - c1)) << 7;
    #pragma unroll
    for (int i = 0; i < (RB*32)/256; ++i){
      int cid = tid + i*256;
      int row = cid >> 5, c16 = cid & 31;
      GLDS16(Wp + (size_t)(o0 + row)*K + kc + c16*4, (char*)buf + cid*16);
    }
  };

  stage(0, Ws[0]);
  for (int c = 0; c < total; ++c){
    float* buf = Ws[c & 1];
    __syncthreads();                       // drains stage(c) (vmcnt) + prev reads
    if (c + 1 < total) stage(c + 1, Ws[(c + 1) & 1]);

    const float* xp = (c < c1) ? x1T : x2T;
    int kc = ((c < c1) ? c : (c - c1)) << 7;
    const float* xq = xp + (size_t)(kc + ksub)*32 + b;
    float xr[16];
    #pragma unroll
    for (int j = 0; j < 16; ++j) xr[j] = xq[j*32];

    #pragma unroll
    for (int r = 0; r < RB; ++r){
      const float* wrow = buf + r*128 + ksub;
      #pragma unroll
      for (int q = 0; q < 4; ++q){
        float4 wv = *(const float4*)(wrow + q*4);
        acc[r] = fmaf(wv.x, xr[q*4+0], acc[r]);
        acc[r] = fmaf(wv.y, xr[q*4+1], acc[r]);
        acc[r] = fmaf(wv.z, xr[q*4+2], acc[r]);
        acc[r] = fmaf(wv.w, xr[q*4+3], acc[r]);
      }
    }
  }

  // cross-group reduce: 8 partials per (r,b)
  __syncthreads();
  float* red = &Ws[0][0];                  // reuse both buffers: 8*RB*32 floats
  int grp = w*2 + g;
  #pragma unroll
  for (int r = 0; r < RB; ++r) red[(grp*RB + r)*32 + b] = acc[r];
  __syncthreads();
  for (int i = tid; i < RB*32; i += 256){
    int r, bb;
    if constexpr (TMODE){ bb = i >> 5; r = i & 31; }   // RB==32 only
    else { r = i >> 5; bb = i & 31; }
    float v = 0.f;
    #pragma unroll
    for (int p = 0; p < 8; ++p) v += red[(p*RB + r)*32 + bb];
    if (bias1) v += bias1[o0 + r];
    if (bias2) v += bias2[o0 + r];
    if constexpr (TMODE) outB[(size_t)bb*ldo + o0 + r] = v;
    else                 outT[(size_t)(o0 + r)*32 + bb] = v;
  }
}

// ---------- LSTM cell ----------
__global__ void k_cell(const float* __restrict__ gT, const float* __restrict__ c_in,
                       float* __restrict__ h_out, float* __restrict__ c_out,
                       float* __restrict__ hT_next, float* __restrict__ h_plain){
  int idx = blockIdx.x*256 + threadIdx.x;
  int b = idx >> 10, j = idx & 1023;
  float gi = gT[j*32 + b];
  float gf = gT[(1024 + j)*32 + b];
  float gg = gT[(2048 + j)*32 + b];
  float go = gT[(3072 + j)*32 + b];
  float cv = c_in[b*1024 + j];
  float cnv = fsig(gf)*cv + fsig(gi)*ftanh(gg);
  float hn  = fsig(go)*ftanh(cnv);
  c_out[b*1024 + j] = cnv;
  h_out[b*1024 + j] = hn;
  if (hT_next) hT_next[j*32 + b] = hn;
  if (h_plain) h_plain[b*1024 + j] = hn;
}

// ---------- preds tail zero ----------
__global__ void k_zerotail(float* __restrict__ preds){
  int i = blockIdx.x*256 + threadIdx.x;          // 32 * 7000 float4
  if (i < 224000){
    int b = i / 7000, t = i % 7000;
    ((float4*)(preds + (size_t)b*CPY + OUTD))[t] = make_float4(0.f, 0.f, 0.f, 0.f);
  }
}

// ---------- copy-scores finalize ----------
__global__ void k_csfinal(const float* __restrict__ csacc, const int* __restrict__ mask,
                          float* __restrict__ cs_out){
  int i = blockIdx.x*256 + threadIdx.x;
  if (i < 16320){
    int b = i / 510, j = i % 510, l = j + 1;
    cs_out[b*510 + j] = (mask[b*512 + l] != 0) ? csacc[b*512 + l] : NEGF;
  }
}

// ---------- serial scatter (numpy last-wins semantics) ----------
__global__ void k_scatter(const int* __restrict__ src, const int* __restrict__ s2c,
                          const float* __restrict__ cs_out, float* __restrict__ preds){
  int b = threadIdx.x;
  if (b < 32){
    for (int j = 0; j < 510; ++j){
      int idx = s2c[src[(j+1)*32 + b]];
      preds[(size_t)b*CPY + idx] = cs_out[b*510 + j];
    }
  }
}

extern "C" void kernel_launch(void* const* d_in, const int* in_sizes, int n_in,
                              void* d_out, int out_size, void* d_ws, size_t ws_size,
                              hipStream_t stream){
  const int*   src    = (const int*)  d_in[0];
  const int*   inp    = (const int*)  d_in[1];
  const float* hidden = (const float*)d_in[2];
  const float* cst    = (const float*)d_in[3];
  const float* enc    = (const float*)d_in[4];
  const int*   mask   = (const int*)  d_in[5];
  const float* selw   = (const float*)d_in[6];
  const int*   s2c    = (const int*)  d_in[7];
  const float* emb    = (const float*)d_in[8];
  const float* W_attn = (const float*)d_in[9];
  const float* b_attn = (const float*)d_in[10];
  const float* v_attn = (const float*)d_in[11];
  const float* W_ih0  = (const float*)d_in[12];
  const float* W_hh0  = (const float*)d_in[13];
  const float* b_ih0  = (const float*)d_in[14];
  const float* b_hh0  = (const float*)d_in[15];
  const float* W_ih1  = (const float*)d_in[16];
  const float* W_hh1  = (const float*)d_in[17];
  const float* b_ih1  = (const float*)d_in[18];
  const float* b_hh1  = (const float*)d_in[19];
  const float* W_fc   = (const float*)d_in[20];
  const float* b_fc   = (const float*)d_in[21];
  const float* W_copy = (const float*)d_in[22];
  const float* b_copy = (const float*)d_in[23];

  if (ws_size < WS_TOTAL) return;   // would corrupt; fail visibly instead

  float* out = (float*)d_out;
  char*  ws  = (char*)d_ws;
  u16*   encbf  = (u16*)  (ws + WS_ENC);
  u16*   wa1t   = (u16*)  (ws + WS_WA1T);
  u16*   wa2t   = (u16*)  (ws + WS_WA2T);
  u16*   wct    = (u16*)  (ws + WS_WCT);
  u16*   htopbf = (u16*)  (ws + WS_HTOPBF);
  float* hpf    = (float*)(ws + WS_HPF);
  float* scores = (float*)(ws + WS_SCORES);
  float* csacc  = (float*)(ws + WS_CSACC);
  float* selp   = (float*)(ws + WS_SELP);
  float* xT     = (float*)(ws + WS_XT);
  float* catT   = (float*)(ws + WS_CATT);
  float* hT0    = (float*)(ws + WS_HT0);
  float* hT1    = (float*)(ws + WS_HT1);
  float* h0T    = (float*)(ws + WS_H0T);
  float* gates  = (float*)(ws + WS_GATES);
  float* h1     = (float*)(ws + WS_H1);

  // converts / transposes
  k_f32_to_bf16<<<2048, 256, 0, stream>>>(enc,    encbf, (LL*BB*H2)/4);
  k_f32_to_bf16<<<512,  256, 0, stream>>>(W_copy, wct,   (DH*H2)/4);
  k_wattn_t<<<dim3(16, 32), 256, 0, stream>>>(W_attn, wa1t, wa2t);
  k_prep<<<32, 256, 0, stream>>>(src, inp, hidden, selw, s2c, emb, mask,
                                 xT, catT, hT0, hT1, htopbf, scores, csacc, selp);

  // h-part: hpf[b][n] = b_attn[n] + h_top @ Wa1
  k_mfma<<<8, 256, 0, stream>>>(htopbf, 1024, 32, wa1t, 1024, 1024,
                                b_attn, 0, nullptr, 0, nullptr, 512, 0, hpf, 8);
  // attention scores: atomicAdd sum_n tanh(enc@Wa2 + hpf) * v_attn
  k_mfma<<<1024, 256, 0, stream>>>(encbf, 1024, LL*BB, wa2t, 1024, 1024,
                                   hpf, 1024, v_attn, 0, scores, 512, 0, nullptr, 8);
  k_softmax_attn<<<32, 256, 0, stream>>>(scores, mask, out + ATTN_OFF);
  k_reads<<<dim3(8, 32), 128, 0, stream>>>(encbf, out + ATTN_OFF, selp, xT, catT);

  // LSTM layer 0: gates = W_ih0 @ x + W_hh0 @ h0 + biases
  k_wstream<16, false><<<256, 256, 0, stream>>>(W_ih0, xT, KX, W_hh0, hT0, DH,
                                                b_ih0, b_hh0, gates, nullptr, 0);
  k_cell<<<128, 256, 0, stream>>>(gates, cst, out + HID_OFF, out + C_OFF, h0T, nullptr);
  // LSTM layer 1
  k_wstream<16, false><<<256, 256, 0, stream>>>(W_ih1, h0T, DH, W_hh1, hT1, DH,
                                                b_ih1, b_hh1, gates, nullptr, 0);
  k_cell<<<128, 256, 0, stream>>>(gates, cst + 32768, out + HID_OFF + 32768,
                                  out + C_OFF + 32768, catT, h1);

  // copy scores: atomicAdd sum_n tanh(enc@W_copy^T + b_copy) * h1 (skip l=0, l=511)
  k_mfma<<<1024, 256, 0, stream>>>(encbf, 1024, LL*BB, wct, 1024, 1024,
                                   b_copy, 0, h1, 1024, csacc, 512, 1, nullptr, 8);

  // generator -> preds[:, :32000]
  k_wstream<32, true><<<1000, 256, 0, stream>>>(W_fc, catT, KX, nullptr, nullptr, 0,
                                                b_fc, nullptr, nullptr, out, (size_t)CPY);
  k_zerotail<<<875, 256, 0, stream>>>(out);
  k_csfinal<<<64, 256, 0, stream>>>(csacc, mask, out + CS_OFF);
  k_scatter<<<1, 64, 0, stream>>>(src, s2c, out + CS_OFF, out);
}

// Round 4
// 397.573 us; speedup vs baseline: 2.2497x; 1.5749x over previous
//
#include <hip/hip_runtime.h>
#include <stdint.h>

typedef unsigned short u16;
typedef unsigned int   u32;
typedef __attribute__((ext_vector_type(8))) short short8;
typedef __attribute__((ext_vector_type(4))) float f32x4;

#define NEGF (-1.0e10f)

// ---------- sizes ----------
static constexpr int LL = 512, BB = 32, EE = 512, H2 = 1024, DH = 1024;
static constexpr int KX = 2560, OUTD = 32000, CPY = 60000;

// ---------- output offsets (floats) ----------
static constexpr size_t HID_OFF   = 1920000;              // 2*32*1024
static constexpr size_t C_OFF     = HID_OFF + 65536;
static constexpr size_t ATTN_OFF  = C_OFF + 65536;        // 32*512
static constexpr size_t CS_OFF    = ATTN_OFF + 16384;     // 32*510

// ---------- workspace offsets (bytes) ----------
static constexpr size_t WS_ENC    = 0;                     // 16384*1024*2 = 33.5MB
static constexpr size_t WS_WA1T   = 33554432;              // 1024*1024*2
static constexpr size_t WS_WA2T   = 35651584;
static constexpr size_t WS_WCT    = 37748736;
static constexpr size_t WS_HPF    = 39845888;              // 32*1024*4
static constexpr size_t WS_SCORES = 39976960;              // 32*512*4
static constexpr size_t WS_CSACC  = 40042496;
static constexpr size_t WS_SELP   = 40108032;
static constexpr size_t WS_XBF    = 40173568;              // 32*2560*2
static constexpr size_t WS_GENBF  = 40337408;              // 32*2560*2
static constexpr size_t WS_H0PBF  = 40501248;              // 32*1024*2
static constexpr size_t WS_H1PBF  = 40566784;              // 32*1024*2
static constexpr size_t WS_H0NBF  = 40632320;              // 32*1024*2
static constexpr size_t WS_GATES  = 40697856;              // 32*4096*4
static constexpr size_t WS_H1     = 41222144;              // 32*1024*4
static constexpr size_t WS_TOTAL  = 41353216;
// aliased (stream-order safe):
static constexpr size_t WS_GPART  = WS_WA1T;               // 4*32*4096*4 = 2MB (wa1t dead after hpf-mfma)
static constexpr size_t WS_TAG    = WS_ENC;                // 32*60000*4 (enc dead after copy-mfma)

// ---------- helpers ----------
__device__ __forceinline__ u16 f2bf(float x){
  u32 u = __builtin_bit_cast(u32, x);
  u32 r = (u + 0x7FFFu + ((u >> 16) & 1u)) >> 16;
  return (u16)r;
}
__device__ __forceinline__ float bf2f(u16 h){
  u32 u = ((u32)h) << 16; return __builtin_bit_cast(float, u);
}
__device__ __forceinline__ float fsig(float x){ return 1.f/(1.f + __expf(-x)); }
__device__ __forceinline__ float ftanh(float x){
  float e = __expf(2.f*x);
  return 1.f - 2.f/(e + 1.f);
}

#define GLDS16(gp, lp) __builtin_amdgcn_global_load_lds( \
    (__attribute__((address_space(1))) void*)(gp), \
    (__attribute__((address_space(3))) void*)(lp), 16, 0, 0)

// ---------- f32 -> bf16 elementwise ----------
__global__ void k_f32_to_bf16(const float* __restrict__ in, u16* __restrict__ out, int n4){
  int stride = gridDim.x * blockDim.x;
  for (int i = blockIdx.x*blockDim.x + threadIdx.x; i < n4; i += stride){
    float4 v = ((const float4*)in)[i];
    u32 lo = (u32)f2bf(v.x) | ((u32)f2bf(v.y) << 16);
    u32 hi = (u32)f2bf(v.z) | ((u32)f2bf(v.w) << 16);
    ((uint2*)out)[i] = make_uint2(lo, hi);
  }
}

// ---------- transpose W_attn (2048k x 1024n) -> Wa1T/Wa2T [n][k] bf16 ----------
__global__ void k_wattn_t(const float* __restrict__ W, u16* __restrict__ wa1t, u16* __restrict__ wa2t){
  __shared__ float Tt[64*65];
  int n0 = blockIdx.x*64, k0 = blockIdx.y*64;
  int t = threadIdx.x;
  int nn = t & 63, kq = t >> 6;
  for (int kk = kq; kk < 64; kk += 4)
    Tt[kk*65 + nn] = W[(size_t)(k0+kk)*1024 + n0 + nn];
  __syncthreads();
  u16* dst = (k0 < 1024) ? wa1t : wa2t;
  int kbase = (k0 < 1024) ? k0 : (k0 - 1024);
  int kk2 = t & 63, nq = t >> 6;
  for (int nn2 = nq; nn2 < 64; nn2 += 4)
    dst[(size_t)(n0+nn2)*1024 + kbase + kk2] = f2bf(Tt[kk2*65 + nn2]);
}

// ---------- prep: embedded, prev-h bf16, zero accum, sel softmax ----------
__global__ void k_prep(const int* __restrict__ src, const int* __restrict__ inp,
                       const float* __restrict__ hidden, const float* __restrict__ selw,
                       const int* __restrict__ s2c, const float* __restrict__ emb,
                       const int* __restrict__ mask,
                       u16* __restrict__ xbf, u16* __restrict__ genbf,
                       u16* __restrict__ h0pbf, u16* __restrict__ h1pbf,
                       float* __restrict__ scores, float* __restrict__ csacc,
                       float* __restrict__ selp)
{
  int b = blockIdx.x, t = threadIdx.x;
  int ib = inp[b];
  for (int h = t; h < 512; h += 256){
    u16 e = f2bf(emb[(size_t)ib*512 + h]);
    xbf[b*2560 + h] = e;              // x = [emb, att, sel]
    genbf[b*2560 + 2048 + h] = e;     // gen = [h1, att, emb]
  }
  for (int k = t; k < 1024; k += 256){
    h0pbf[b*1024 + k] = f2bf(hidden[b*1024 + k]);
    h1pbf[b*1024 + k] = f2bf(hidden[32768 + b*1024 + k]);
  }
  for (int l = t; l < 512; l += 256){
    scores[b*512 + l] = 0.f;
    csacc[b*512 + l] = 0.f;
  }
  __shared__ float red[256];
  float lg[2];
  #pragma unroll
  for (int i = 0; i < 2; ++i){
    int j = t + i*256;
    lg[i] = NEGF;
    if (j < 510){
      int cs = s2c[src[(j+1)*32 + b]];
      if (cs == ib) lg[i] = selw[b*510 + j];
    }
  }
  red[t] = fmaxf(lg[0], lg[1]); __syncthreads();
  for (int s = 128; s > 0; s >>= 1){ if (t < s) red[t] = fmaxf(red[t], red[t+s]); __syncthreads(); }
  float mx = red[0]; __syncthreads();
  float e0 = (t < 510)     ? __expf(lg[0] - mx) : 0.f;
  float e1 = (t+256 < 510) ? __expf(lg[1] - mx) : 0.f;
  red[t] = e0 + e1; __syncthreads();
  for (int s = 128; s > 0; s >>= 1){ if (t < s) red[t] += red[t+s]; __syncthreads(); }
  float inv = 1.f / red[0];
  #pragma unroll
  for (int i = 0; i < 2; ++i){
    int j = t + i*256;
    if (j < 510){
      float v = ((i == 0) ? e0 : e1) * inv;
      int l = j + 1;
      selp[b*512 + l] = (mask[b*512 + l] != 0) ? v : NEGF;
    }
  }
}

// ---------- unified bf16 MFMA GEMM (128x128 tile, BK=64) — enc attention/copy ----------
__launch_bounds__(256)
__global__ void k_mfma(const u16* __restrict__ A, int lda, int Mvalid,
                       const u16* __restrict__ Bmat, int ldb, int K,
                       const float* __restrict__ preadd, int spa,
                       const float* __restrict__ dotw, int sdw,
                       float* __restrict__ dotout, int Ldot, int skipedge,
                       float* __restrict__ outstore, int NT)
{
  __shared__ u16 As[128*64];
  __shared__ u16 Bs[128*64];
  int nwg = gridDim.x, bid = blockIdx.x;
  int q = nwg >> 3, r = nwg & 7, xc = bid & 7, ix = bid >> 3;
  int wg = (xc < r ? xc*(q+1) : r*(q+1) + (xc - r)*q) + ix;
  int mt = wg / NT, nt = wg % NT;
  int m0 = mt * 128, n0 = nt * 128;
  int tid = threadIdx.x, lane = tid & 63, wid = tid >> 6;
  int wm = wid >> 1, wn = wid & 1;

  f32x4 acc[4][4];
  #pragma unroll
  for (int i = 0; i < 4; ++i)
    #pragma unroll
    for (int j = 0; j < 4; ++j)
      acc[i][j] = (f32x4){0.f, 0.f, 0.f, 0.f};

  int srow = lane >> 3;
  int soff = ((lane & 7) ^ srow) * 8;

  for (int k0 = 0; k0 < K; k0 += 64){
    __syncthreads();
    #pragma unroll
    for (int j = 0; j < 4; ++j){
      int qq = wid*4 + j;
      int ra = m0 + qq*8 + srow; if (ra >= Mvalid) ra = Mvalid - 1;
      GLDS16(A + (size_t)ra*lda + k0 + soff, (char*)As + qq*1024 + lane*16);
      int rb = n0 + qq*8 + srow;
      GLDS16(Bmat + (size_t)rb*ldb + k0 + soff, (char*)Bs + qq*1024 + lane*16);
    }
    __syncthreads();
    #pragma unroll
    for (int kk = 0; kk < 2; ++kk){
      short8 af[4], bfr[4];
      #pragma unroll
      for (int mi = 0; mi < 4; ++mi){
        int rr = wm*64 + mi*16 + (lane & 15);
        int kb = (kk*64 + ((lane >> 4) << 4)) ^ ((rr & 7) << 4);
        af[mi] = *(const short8*)((const char*)As + rr*128 + kb);
      }
      #pragma unroll
      for (int nj = 0; nj < 4; ++nj){
        int rr = wn*64 + nj*16 + (lane & 15);
        int kb = (kk*64 + ((lane >> 4) << 4)) ^ ((rr & 7) << 4);
        bfr[nj] = *(const short8*)((const char*)Bs + rr*128 + kb);
      }
      #pragma unroll
      for (int mi = 0; mi < 4; ++mi)
        #pragma unroll
        for (int nj = 0; nj < 4; ++nj)
          acc[mi][nj] = __builtin_amdgcn_mfma_f32_16x16x32_bf16(af[mi], bfr[nj], acc[mi][nj], 0, 0, 0);
    }
  }

  int g = lane >> 4, cn = lane & 15;
  if (outstore){
    int Nld = NT * 128;
    #pragma unroll
    for (int mi = 0; mi < 4; ++mi)
      #pragma unroll
      for (int rr2 = 0; rr2 < 4; ++rr2){
        int row = m0 + wm*64 + mi*16 + g*4 + rr2;
        if (row < Mvalid){
          #pragma unroll
          for (int nj = 0; nj < 4; ++nj){
            int n = n0 + wn*64 + nj*16 + cn;
            outstore[(size_t)row*Nld + n] = acc[mi][nj][rr2] + preadd[(size_t)(row & 31)*spa + n];
          }
        }
      }
  } else {
    #pragma unroll
    for (int mi = 0; mi < 4; ++mi)
      #pragma unroll
      for (int rr2 = 0; rr2 < 4; ++rr2){
        int row = m0 + wm*64 + mi*16 + g*4 + rr2;
        int bb = row & 31;
        float part = 0.f;
        #pragma unroll
        for (int nj = 0; nj < 4; ++nj){
          int n = n0 + wn*64 + nj*16 + cn;
          float tv = ftanh(acc[mi][nj][rr2] + preadd[(size_t)bb*spa + n]);
          part = fmaf(tv, dotw[(size_t)bb*sdw + n], part);
        }
        part += __shfl_xor(part, 1);
        part += __shfl_xor(part, 2);
        part += __shfl_xor(part, 4);
        part += __shfl_xor(part, 8);
        if (cn == 0){
          int l = row >> 5;
          if (!skipedge || (l > 0 && l < Ldot - 1))
            atomicAdd(&dotout[(size_t)bb*Ldot + l], part);
        }
      }
  }
}

// ---------- attention softmax over L per b ----------
__global__ void k_softmax_attn(const float* __restrict__ scores, const int* __restrict__ mask,
                               float* __restrict__ attnw){
  int b = blockIdx.x, t = threadIdx.x;
  __shared__ float red[256];
  float v0 = scores[b*512 + t];
  float v1 = scores[b*512 + 256 + t];
  if (mask[b*512 + t] == 0) v0 = NEGF;
  if (mask[b*512 + 256 + t] == 0) v1 = NEGF;
  red[t] = fmaxf(v0, v1); __syncthreads();
  for (int s = 128; s > 0; s >>= 1){ if (t < s) red[t] = fmaxf(red[t], red[t+s]); __syncthreads(); }
  float mx = red[0]; __syncthreads();
  float e0 = __expf(v0 - mx), e1 = __expf(v1 - mx);
  red[t] = e0 + e1; __syncthreads();
  for (int s = 128; s > 0; s >>= 1){ if (t < s) red[t] += red[t+s]; __syncthreads(); }
  float inv = 1.f / red[0];
  attnw[b*512 + t] = e0 * inv;
  attnw[b*512 + 256 + t] = e1 * inv;
}

// ---------- attentive & selective reads -> bf16 x/gen pieces ----------
__global__ void k_reads(const u16* __restrict__ encbf, const float* __restrict__ attnw,
                        const float* __restrict__ selp,
                        u16* __restrict__ xbf, u16* __restrict__ genbf){
  int b = blockIdx.y;
  int h = blockIdx.x*128 + threadIdx.x;
  float aa = 0.f, as = 0.f;
  #pragma unroll 4
  for (int l = 0; l < 512; ++l){
    float e = bf2f(encbf[((size_t)l*32 + b)*1024 + h]);
    aa = fmaf(attnw[b*512 + l], e, aa);
    if (l >= 1 && l < 511) as = fmaf(selp[b*512 + l], e, as);
  }
  u16 ab = f2bf(aa);
  xbf[b*2560 + 512 + h]  = ab;
  xbf[b*2560 + 1536 + h] = f2bf(as);
  genbf[b*2560 + 1024 + h] = ab;
}

// ---------- fused-convert MFMA GEMM: out[b][o] = bias + sum_k W[o][k]*x[b][k] ----------
// W f32 row-major (M x K), x bf16 [32][K]. M-tile 64/block, 4 waves.
// grid.y = split-K part index (cps chunks of 64 each).
// Sync is count-independent: lgkmcnt(0)+vmcnt(0) before barrier2 (only the
// B-stage GLDS is outstanding there); A-prefetch is issued AFTER barrier2 so
// it overlaps compute and is consumed (auto-waited) by next iter's pack.
__launch_bounds__(256)
__global__ void k_wgemm(const float* __restrict__ W1, const u16* __restrict__ xb1, int K1,
                        const float* __restrict__ W2, const u16* __restrict__ xb2, int K2,
                        const float* __restrict__ bias1, const float* __restrict__ bias2,
                        float* __restrict__ outB, int ldo, int cps)
{
  __shared__ u16 As[64*64];   // 8KB, [row][64k], 128B rows, XOR-swizzled slots
  __shared__ u16 Bs[32*64];   // 4KB
  const int tid = threadIdx.x, lane = tid & 63, w = tid >> 6;
  const int o0 = blockIdx.x * 64;
  const int c1 = K1 >> 6;
  const int c0 = blockIdx.y * cps;

  f32x4 acc[2];
  acc[0] = (f32x4){0.f,0.f,0.f,0.f};
  acc[1] = (f32x4){0.f,0.f,0.f,0.f};

  const int ar = tid >> 2, akq = (tid & 3) * 16;   // A: row, k-offset (floats)
  const int aswz = (ar & 7) << 4;
  const int brow = tid >> 3, pslot = tid & 7;
  const int lslot = pslot ^ (brow & 7);            // pre-swizzled B source slot

  float4 aA[4], aB[4];

  auto aload = [&](int c, float4* dst){
    const float* Wp; int Kp, kc;
    if (c < c1){ Wp = W1; Kp = K1; kc = c << 6; }
    else       { Wp = W2; Kp = K2; kc = (c - c1) << 6; }
    const float4* p = (const float4*)(Wp + (size_t)(o0 + ar)*Kp + kc + akq);
    dst[0] = p[0]; dst[1] = p[1]; dst[2] = p[2]; dst[3] = p[3];
  };

  auto body = [&](int c, float4* cur, float4* nxt, bool more){
    // barrier1: all waves done reading As/Bs of previous chunk
    asm volatile("s_waitcnt lgkmcnt(0)" ::: "memory");
    __builtin_amdgcn_s_barrier();
    // B stage (GLDS, linear dest / pre-swizzled source)
    {
      const u16* xp; int Kp, kc;
      if (c < c1){ xp = xb1; Kp = K1; kc = c << 6; }
      else       { xp = xb2; Kp = K2; kc = (c - c1) << 6; }
      GLDS16(xp + (size_t)brow*Kp + kc + lslot*8, (char*)Bs + tid*16);
    }
    // A pack + swizzled ds_write (compiler auto-waits cur's loads here)
    u32 p0 = (u32)f2bf(cur[0].x) | ((u32)f2bf(cur[0].y) << 16);
    u32 p1 = (u32)f2bf(cur[0].z) | ((u32)f2bf(cur[0].w) << 16);
    u32 p2 = (u32)f2bf(cur[1].x) | ((u32)f2bf(cur[1].y) << 16);
    u32 p3 = (u32)f2bf(cur[1].z) | ((u32)f2bf(cur[1].w) << 16);
    u32 p4 = (u32)f2bf(cur[2].x) | ((u32)f2bf(cur[2].y) << 16);
    u32 p5 = (u32)f2bf(cur[2].z) | ((u32)f2bf(cur[2].w) << 16);
    u32 p6 = (u32)f2bf(cur[3].x) | ((u32)f2bf(cur[3].y) << 16);
    u32 p7 = (u32)f2bf(cur[3].z) | ((u32)f2bf(cur[3].w) << 16);
    char* rowp = (char*)As + ar*128;
    *(uint4*)(rowp + ((akq*2)      ^ aswz)) = make_uint4(p0,p1,p2,p3);
    *(uint4*)(rowp + ((akq*2 + 16) ^ aswz)) = make_uint4(p4,p5,p6,p7);
    // barrier2: ds_writes done (lgkm) AND B-stage GLDS landed (vmcnt(0) —
    // count-independent; only the GLDS is outstanding at this point)
    asm volatile("s_waitcnt lgkmcnt(0)\n\ts_waitcnt vmcnt(0)" ::: "memory");
    __builtin_amdgcn_s_barrier();
    // prefetch next A chunk — issued after barrier2, overlaps compute below
    if (more) aload(c + 1, nxt);
    // compute: 2 k-halves x 2 n-frags
    #pragma unroll
    for (int kk = 0; kk < 2; ++kk){
      int rrA = w*16 + (lane & 15);
      int kb  = kk*64 + ((lane >> 4) << 4);
      short8 af = *(const short8*)((const char*)As + rrA*128 + (kb ^ ((rrA & 7) << 4)));
      #pragma unroll
      for (int nj = 0; nj < 2; ++nj){
        int rrB = nj*16 + (lane & 15);
        short8 bfv = *(const short8*)((const char*)Bs + rrB*128 + (kb ^ ((rrB & 7) << 4)));
        acc[nj] = __builtin_amdgcn_mfma_f32_16x16x32_bf16(af, bfv, acc[nj], 0, 0, 0);
      }
    }
  };

  aload(c0, aA);
  for (int li = 0; li < cps; li += 2){          // cps is always even
    body(c0 + li,     aA, aB, true);
    body(c0 + li + 1, aB, aA, (li + 2) < cps);
  }

  // epilogue
  int g = lane >> 4, cn = lane & 15;
  int ob = o0 + w*16 + g*4;
  float* outP = outB + (size_t)blockIdx.y * 32 * (size_t)ldo;
  float4 badd = make_float4(0.f,0.f,0.f,0.f);
  if (blockIdx.y == 0){
    if (bias1){ float4 t = *(const float4*)(bias1 + ob);
      badd.x += t.x; badd.y += t.y; badd.z += t.z; badd.w += t.w; }
    if (bias2){ float4 t = *(const float4*)(bias2 + ob);
      badd.x += t.x; badd.y += t.y; badd.z += t.z; badd.w += t.w; }
  }
  #pragma unroll
  for (int nj = 0; nj < 2; ++nj){
    int bcol = nj*16 + cn;
    float4 v = make_float4(acc[nj][0] + badd.x, acc[nj][1] + badd.y,
                           acc[nj][2] + badd.z, acc[nj][3] + badd.w);
    *(float4*)(outP + (size_t)bcol*ldo + ob) = v;
  }
}

// ---------- split-K reduce for gates (4 parts) ----------
__global__ void k_gred(const float* __restrict__ part, float* __restrict__ g){
  int i = blockIdx.x*256 + threadIdx.x;   // 131072
  g[i] = part[i] + part[131072 + i] + part[262144 + i] + part[393216 + i];
}

// ---------- LSTM cell (gates layout [b][4096]) ----------
__global__ void k_cell(const float* __restrict__ g, const float* __restrict__ c_in,
                       float* __restrict__ h_out, float* __restrict__ c_out,
                       u16* __restrict__ hbf, int hld, float* __restrict__ h_plain){
  int idx = blockIdx.x*256 + threadIdx.x;
  int b = idx >> 10, j = idx & 1023;
  const float* gb = g + (size_t)b*4096;
  float gi = gb[j];
  float gf = gb[1024 + j];
  float gg = gb[2048 + j];
  float go = gb[3072 + j];
  float cv = c_in[b*1024 + j];
  float cnv = fsig(gf)*cv + fsig(gi)*ftanh(gg);
  float hn  = fsig(go)*ftanh(cnv);
  c_out[b*1024 + j] = cnv;
  h_out[b*1024 + j] = hn;
  hbf[(size_t)b*hld + j] = f2bf(hn);
  if (h_plain) h_plain[b*1024 + j] = hn;
}

// ---------- preds tail zero ----------
__global__ void k_zerotail(float* __restrict__ preds){
  int i = blockIdx.x*256 + threadIdx.x;          // 32 * 7000 float4
  if (i < 224000){
    int b = i / 7000, t = i % 7000;
    ((float4*)(preds + (size_t)b*CPY + OUTD))[t] = make_float4(0.f, 0.f, 0.f, 0.f);
  }
}

// ---------- copy-scores finalize ----------
__global__ void k_csfinal(const float* __restrict__ csacc, const int* __restrict__ mask,
                          float* __restrict__ cs_out){
  int i = blockIdx.x*256 + threadIdx.x;
  if (i < 16320){
    int b = i / 510, j = i % 510, l = j + 1;
    cs_out[b*510 + j] = (mask[b*512 + l] != 0) ? csacc[b*512 + l] : NEGF;
  }
}

// ---------- parallel scatter, numpy last-wins via atomicMax tag ----------
__global__ void k_tag_init(const int* __restrict__ src, const int* __restrict__ s2c,
                           int* __restrict__ tag){
  int i = blockIdx.x*256 + threadIdx.x;
  if (i < 16320){
    int b = i / 510, j = i % 510;
    tag[(size_t)b*CPY + s2c[src[(j+1)*32 + b]]] = -1;
  }
}
__global__ void k_tag_max(const int* __restrict__ src, const int* __restrict__ s2c,
                          int* __restrict__ tag){
  int i = blockIdx.x*256 + threadIdx.x;
  if (i < 16320){
    int b = i / 510, j = i % 510;
    atomicMax(&tag[(size_t)b*CPY + s2c[src[(j+1)*32 + b]]], j);
  }
}
__global__ void k_tag_write(const int* __restrict__ src, const int* __restrict__ s2c,
                            const int* __restrict__ tag, const float* __restrict__ cs,
                            float* __restrict__ preds){
  int i = blockIdx.x*256 + threadIdx.x;
  if (i < 16320){
    int b = i / 510, j = i % 510;
    int idx = s2c[src[(j+1)*32 + b]];
    if (tag[(size_t)b*CPY + idx] == j)
      preds[(size_t)b*CPY + idx] = cs[b*510 + j];
  }
}

extern "C" void kernel_launch(void* const* d_in, const int* in_sizes, int n_in,
                              void* d_out, int out_size, void* d_ws, size_t ws_size,
                              hipStream_t stream){
  const int*   src    = (const int*)  d_in[0];
  const int*   inp    = (const int*)  d_in[1];
  const float* hidden = (const float*)d_in[2];
  const float* cst    = (const float*)d_in[3];
  const float* enc    = (const float*)d_in[4];
  const int*   mask   = (const int*)  d_in[5];
  const float* selw   = (const float*)d_in[6];
  const int*   s2c    = (const int*)  d_in[7];
  const float* emb    = (const float*)d_in[8];
  const float* W_attn = (const float*)d_in[9];
  const float* b_attn = (const float*)d_in[10];
  const float* v_attn = (const float*)d_in[11];
  const float* W_ih0  = (const float*)d_in[12];
  const float* W_hh0  = (const float*)d_in[13];
  const float* b_ih0  = (const float*)d_in[14];
  const float* b_hh0  = (const float*)d_in[15];
  const float* W_ih1  = (const float*)d_in[16];
  const float* W_hh1  = (const float*)d_in[17];
  const float* b_ih1  = (const float*)d_in[18];
  const float* b_hh1  = (const float*)d_in[19];
  const float* W_fc   = (const float*)d_in[20];
  const float* b_fc   = (const float*)d_in[21];
  const float* W_copy = (const float*)d_in[22];
  const float* b_copy = (const float*)d_in[23];

  if (ws_size < WS_TOTAL) return;

  float* out = (float*)d_out;
  char*  ws  = (char*)d_ws;
  u16*   encbf  = (u16*)  (ws + WS_ENC);
  u16*   wa1t   = (u16*)  (ws + WS_WA1T);
  u16*   wa2t   = (u16*)  (ws + WS_WA2T);
  u16*   wct    = (u16*)  (ws + WS_WCT);
  float* hpf    = (float*)(ws + WS_HPF);
  float* scores = (float*)(ws + WS_SCORES);
  float* csacc  = (float*)(ws + WS_CSACC);
  float* selp   = (float*)(ws + WS_SELP);
  u16*   xbf    = (u16*)  (ws + WS_XBF);
  u16*   genbf  = (u16*)  (ws + WS_GENBF);
  u16*   h0pbf  = (u16*)  (ws + WS_H0PBF);
  u16*   h1pbf  = (u16*)  (ws + WS_H1PBF);
  u16*   h0nbf  = (u16*)  (ws + WS_H0NBF);
  float* gates  = (float*)(ws + WS_GATES);
  float* gpart  = (float*)(ws + WS_GPART);
  float* h1     = (float*)(ws + WS_H1);
  int*   tag    = (int*)  (ws + WS_TAG);

  // converts / transposes / prep
  k_f32_to_bf16<<<2048, 256, 0, stream>>>(enc,    encbf, (LL*BB*H2)/4);
  k_f32_to_bf16<<<512,  256, 0, stream>>>(W_copy, wct,   (DH*H2)/4);
  k_wattn_t<<<dim3(16, 32), 256, 0, stream>>>(W_attn, wa1t, wa2t);
  k_prep<<<32, 256, 0, stream>>>(src, inp, hidden, selw, s2c, emb, mask,
                                 xbf, genbf, h0pbf, h1pbf, scores, csacc, selp);

  // h-part: hpf[b][n] = b_attn[n] + h_top @ Wa1
  k_mfma<<<8, 256, 0, stream>>>(h1pbf, 1024, 32, wa1t, 1024, 1024,
                                b_attn, 0, nullptr, 0, nullptr, 512, 0, hpf, 8);
  // attention scores
  k_mfma<<<1024, 256, 0, stream>>>(encbf, 1024, LL*BB, wa2t, 1024, 1024,
                                   hpf, 1024, v_attn, 0, scores, 512, 0, nullptr, 8);
  k_softmax_attn<<<32, 256, 0, stream>>>(scores, mask, out + ATTN_OFF);
  k_reads<<<dim3(8, 32), 128, 0, stream>>>(encbf, out + ATTN_OFF, selp, xbf, genbf);

  // LSTM layer 0 gates: W_ih0@x + W_hh0@h0prev  (split-K=4, 56 chunks -> 14/part)
  k_wgemm<<<dim3(64, 4), 256, 0, stream>>>(W_ih0, xbf, KX, W_hh0, h0pbf, DH,
                                           b_ih0, b_hh0, gpart, 4096, 14);
  k_gred<<<512, 256, 0, stream>>>(gpart, gates);
  k_cell<<<128, 256, 0, stream>>>(gates, cst, out + HID_OFF, out + C_OFF,
                                  h0nbf, 1024, nullptr);
  // LSTM layer 1 gates: W_ih1@h0new + W_hh1@h1prev  (32 chunks -> 8/part)
  k_wgemm<<<dim3(64, 4), 256, 0, stream>>>(W_ih1, h0nbf, DH, W_hh1, h1pbf, DH,
                                           b_ih1, b_hh1, gpart, 4096, 8);
  k_gred<<<512, 256, 0, stream>>>(gpart, gates);
  k_cell<<<128, 256, 0, stream>>>(gates, cst + 32768, out + HID_OFF + 32768,
                                  out + C_OFF + 32768, genbf, 2560, h1);

  // copy scores (needs h1, encbf)
  k_mfma<<<1024, 256, 0, stream>>>(encbf, 1024, LL*BB, wct, 1024, 1024,
                                   b_copy, 0, h1, 1024, csacc, 512, 1, nullptr, 8);

  // generator -> preds[:, :32000]  (40 chunks, no split)
  k_wgemm<<<dim3(500, 1), 256, 0, stream>>>(W_fc, genbf, KX, nullptr, nullptr, 0,
                                            b_fc, nullptr, out, CPY, 40);
  k_zerotail<<<875, 256, 0, stream>>>(out);
  k_csfinal<<<64, 256, 0, stream>>>(csacc, mask, out + CS_OFF);

  // scatter (last-wins)
  k_tag_init <<<64, 256, 0, stream>>>(src, s2c, tag);
  k_tag_max  <<<64, 256, 0, stream>>>(src, s2c, tag);
  k_tag_write<<<64, 256, 0, stream>>>(src, s2c, tag, out + CS_OFF, out);
}

// Round 5
// 395.608 us; speedup vs baseline: 2.2608x; 1.0050x over previous
//
#include <hip/hip_runtime.h>
#include <stdint.h>

typedef unsigned short u16;
typedef unsigned int   u32;
typedef __attribute__((ext_vector_type(8))) short short8;
typedef __attribute__((ext_vector_type(4))) float f32x4;

#define NEGF (-1.0e10f)

// ---------- sizes ----------
static constexpr int LL = 512, BB = 32, EE = 512, H2 = 1024, DH = 1024;
static constexpr int KX = 2560, OUTD = 32000, CPY = 60000;

// ---------- output offsets (floats) ----------
static constexpr size_t HID_OFF   = 1920000;              // 2*32*1024
static constexpr size_t C_OFF     = HID_OFF + 65536;
static constexpr size_t ATTN_OFF  = C_OFF + 65536;        // 32*512
static constexpr size_t CS_OFF    = ATTN_OFF + 16384;     // 32*510

// ---------- workspace offsets (bytes) ----------
static constexpr size_t WS_ENC    = 0;                     // 16384*1024*2 = 33.5MB
static constexpr size_t WS_WA1T   = 33554432;              // 1024*1024*2
static constexpr size_t WS_WA2T   = 35651584;
static constexpr size_t WS_WCT    = 37748736;
static constexpr size_t WS_HPF    = 39845888;              // 32*1024*4
static constexpr size_t WS_SCORES = 39976960;              // 32*512*4
static constexpr size_t WS_CSACC  = 40042496;
static constexpr size_t WS_SELP   = 40108032;
static constexpr size_t WS_XBF    = 40173568;              // 32*2560*2
static constexpr size_t WS_GENBF  = 40337408;              // 32*2560*2
static constexpr size_t WS_H0PBF  = 40501248;              // 32*1024*2
static constexpr size_t WS_H1PBF  = 40566784;              // 32*1024*2
static constexpr size_t WS_H0NBF  = 40632320;              // 32*1024*2
static constexpr size_t WS_H1     = 41222144;              // 32*1024*4
static constexpr size_t WS_TOTAL  = 41353216;
// aliased (stream-order safe):
static constexpr size_t WS_GPART  = WS_WA1T;               // 4*32*4096*4 = 2MB (wa1t dead after hpf-mfma)
static constexpr size_t WS_TAG    = WS_ENC;                // 32*60000*4 (enc dead after copy-mfma)

// ---------- helpers ----------
__device__ __forceinline__ u16 f2bf(float x){
  u32 u = __builtin_bit_cast(u32, x);
  u32 r = (u + 0x7FFFu + ((u >> 16) & 1u)) >> 16;
  return (u16)r;
}
__device__ __forceinline__ float bf2f(u16 h){
  u32 u = ((u32)h) << 16; return __builtin_bit_cast(float, u);
}
__device__ __forceinline__ float fsig(float x){ return 1.f/(1.f + __expf(-x)); }
__device__ __forceinline__ float ftanh(float x){
  float e = __expf(2.f*x);
  return 1.f - 2.f/(e + 1.f);
}

#define GLDS16(gp, lp) __builtin_amdgcn_global_load_lds( \
    (__attribute__((address_space(1))) void*)(gp), \
    (__attribute__((address_space(3))) void*)(lp), 16, 0, 0)

// ---------- f32 -> bf16 elementwise ----------
__global__ void k_f32_to_bf16(const float* __restrict__ in, u16* __restrict__ out, int n4){
  int stride = gridDim.x * blockDim.x;
  for (int i = blockIdx.x*blockDim.x + threadIdx.x; i < n4; i += stride){
    float4 v = ((const float4*)in)[i];
    u32 lo = (u32)f2bf(v.x) | ((u32)f2bf(v.y) << 16);
    u32 hi = (u32)f2bf(v.z) | ((u32)f2bf(v.w) << 16);
    ((uint2*)out)[i] = make_uint2(lo, hi);
  }
}

// ---------- transpose W_attn (2048k x 1024n) -> Wa1T/Wa2T [n][k] bf16 ----------
__global__ void k_wattn_t(const float* __restrict__ W, u16* __restrict__ wa1t, u16* __restrict__ wa2t){
  __shared__ float Tt[64*65];
  int n0 = blockIdx.x*64, k0 = blockIdx.y*64;
  int t = threadIdx.x;
  int nn = t & 63, kq = t >> 6;
  for (int kk = kq; kk < 64; kk += 4)
    Tt[kk*65 + nn] = W[(size_t)(k0+kk)*1024 + n0 + nn];
  __syncthreads();
  u16* dst = (k0 < 1024) ? wa1t : wa2t;
  int kbase = (k0 < 1024) ? k0 : (k0 - 1024);
  int kk2 = t & 63, nq = t >> 6;
  for (int nn2 = nq; nn2 < 64; nn2 += 4)
    dst[(size_t)(n0+nn2)*1024 + kbase + kk2] = f2bf(Tt[kk2*65 + nn2]);
}

// ---------- prep: embedded, prev-h bf16, zero accum, sel softmax ----------
__global__ void k_prep(const int* __restrict__ src, const int* __restrict__ inp,
                       const float* __restrict__ hidden, const float* __restrict__ selw,
                       const int* __restrict__ s2c, const float* __restrict__ emb,
                       const int* __restrict__ mask,
                       u16* __restrict__ xbf, u16* __restrict__ genbf,
                       u16* __restrict__ h0pbf, u16* __restrict__ h1pbf,
                       float* __restrict__ scores, float* __restrict__ csacc,
                       float* __restrict__ selp)
{
  int b = blockIdx.x, t = threadIdx.x;
  int ib = inp[b];
  for (int h = t; h < 512; h += 256){
    u16 e = f2bf(emb[(size_t)ib*512 + h]);
    xbf[b*2560 + h] = e;              // x = [emb, att, sel]
    genbf[b*2560 + 2048 + h] = e;     // gen = [h1, att, emb]
  }
  for (int k = t; k < 1024; k += 256){
    h0pbf[b*1024 + k] = f2bf(hidden[b*1024 + k]);
    h1pbf[b*1024 + k] = f2bf(hidden[32768 + b*1024 + k]);
  }
  for (int l = t; l < 512; l += 256){
    scores[b*512 + l] = 0.f;
    csacc[b*512 + l] = 0.f;
  }
  __shared__ float red[256];
  float lg[2];
  #pragma unroll
  for (int i = 0; i < 2; ++i){
    int j = t + i*256;
    lg[i] = NEGF;
    if (j < 510){
      int cs = s2c[src[(j+1)*32 + b]];
      if (cs == ib) lg[i] = selw[b*510 + j];
    }
  }
  red[t] = fmaxf(lg[0], lg[1]); __syncthreads();
  for (int s = 128; s > 0; s >>= 1){ if (t < s) red[t] = fmaxf(red[t], red[t+s]); __syncthreads(); }
  float mx = red[0]; __syncthreads();
  float e0 = (t < 510)     ? __expf(lg[0] - mx) : 0.f;
  float e1 = (t+256 < 510) ? __expf(lg[1] - mx) : 0.f;
  red[t] = e0 + e1; __syncthreads();
  for (int s = 128; s > 0; s >>= 1){ if (t < s) red[t] += red[t+s]; __syncthreads(); }
  float inv = 1.f / red[0];
  #pragma unroll
  for (int i = 0; i < 2; ++i){
    int j = t + i*256;
    if (j < 510){
      float v = ((i == 0) ? e0 : e1) * inv;
      int l = j + 1;
      selp[b*512 + l] = (mask[b*512 + l] != 0) ? v : NEGF;
    }
  }
}

// ---------- bf16 MFMA GEMM, 128x128 tile, BK=32, double-buffered LDS ----------
// One __syncthreads per K-step: its implicit vmcnt(0) drains the GLDS issued
// one full compute phase earlier (cheap); next tile's GLDS is issued AFTER the
// barrier into the other buffer (disjoint), so nothing fresh is drained.
__launch_bounds__(256)
__global__ void k_mfma(const u16* __restrict__ A, int lda, int Mvalid,
                       const u16* __restrict__ Bmat, int ldb, int K,
                       const float* __restrict__ preadd, int spa,
                       const float* __restrict__ dotw, int sdw,
                       float* __restrict__ dotout, int Ldot, int skipedge,
                       float* __restrict__ outstore, int NT)
{
  __shared__ u16 As[2][128*32];   // 8KB each, rows of 64B, slot-xor swizzled
  __shared__ u16 Bs[2][128*32];
  int nwg = gridDim.x, bid = blockIdx.x;
  int q = nwg >> 3, r = nwg & 7, xc = bid & 7, ix = bid >> 3;
  int wg = (xc < r ? xc*(q+1) : r*(q+1) + (xc - r)*q) + ix;   // bijective XCD swizzle
  int mt = wg / NT, nt = wg % NT;
  int m0 = mt * 128, n0 = nt * 128;
  int tid = threadIdx.x, lane = tid & 63, wid = tid >> 6;
  int wm = wid >> 1, wn = wid & 1;

  f32x4 acc[4][4];
  #pragma unroll
  for (int i = 0; i < 4; ++i)
    #pragma unroll
    for (int j = 0; j < 4; ++j)
      acc[i][j] = (f32x4){0.f, 0.f, 0.f, 0.f};

  // staging: chunk c in {tid, tid+256}; (row, slot) = (c>>2, c&3);
  // source col = (slot ^ xv(row))*8 elements, dest linear (GLDS constraint)
  int r0 = tid >> 2,          s0 = tid & 3;
  int r1 = (tid + 256) >> 2;  // slot same (256%4==0)
  int xv0 = (r0 ^ (r0 >> 2)) & 3, xv1 = (r1 ^ (r1 >> 2)) & 3;
  int sc0 = (s0 ^ xv0) << 3,      sc1 = (s0 ^ xv1) << 3;   // element offsets
  int raA0 = m0 + r0; if (raA0 >= Mvalid) raA0 = Mvalid - 1;
  int raA1 = m0 + r1; if (raA1 >= Mvalid) raA1 = Mvalid - 1;
  int rbB0 = n0 + r0, rbB1 = n0 + r1;

  auto stage = [&](int k0, u16* asb, u16* bsb){
    GLDS16(A    + (size_t)raA0*lda + k0 + sc0, (char*)asb + tid*16);
    GLDS16(A    + (size_t)raA1*lda + k0 + sc1, (char*)asb + (tid+256)*16);
    GLDS16(Bmat + (size_t)rbB0*ldb + k0 + sc0, (char*)bsb + tid*16);
    GLDS16(Bmat + (size_t)rbB1*ldb + k0 + sc1, (char*)bsb + (tid+256)*16);
  };

  int KT = K >> 5;
  stage(0, As[0], Bs[0]);
  for (int kt = 0; kt < KT; ++kt){
    __syncthreads();                          // drains stage(kt) (1 phase old)
    if (kt + 1 < KT) stage((kt+1) << 5, As[(kt+1) & 1], Bs[(kt+1) & 1]);
    const char* ap = (const char*)As[kt & 1];
    const char* bp = (const char*)Bs[kt & 1];
    short8 af[4], bfr[4];
    #pragma unroll
    for (int mi = 0; mi < 4; ++mi){
      int rr = wm*64 + mi*16 + (lane & 15);
      int xv = (rr ^ (rr >> 2)) & 3;
      af[mi] = *(const short8*)(ap + rr*64 + (((lane >> 4) ^ xv) << 4));
    }
    #pragma unroll
    for (int nj = 0; nj < 4; ++nj){
      int rr = wn*64 + nj*16 + (lane & 15);
      int xv = (rr ^ (rr >> 2)) & 3;
      bfr[nj] = *(const short8*)(bp + rr*64 + (((lane >> 4) ^ xv) << 4));
    }
    #pragma unroll
    for (int mi = 0; mi < 4; ++mi)
      #pragma unroll
      for (int nj = 0; nj < 4; ++nj)
        acc[mi][nj] = __builtin_amdgcn_mfma_f32_16x16x32_bf16(af[mi], bfr[nj], acc[mi][nj], 0, 0, 0);
  }

  int g = lane >> 4, cn = lane & 15;
  if (outstore){
    int Nld = NT * 128;
    #pragma unroll
    for (int mi = 0; mi < 4; ++mi)
      #pragma unroll
      for (int rr2 = 0; rr2 < 4; ++rr2){
        int row = m0 + wm*64 + mi*16 + g*4 + rr2;
        if (row < Mvalid){
          #pragma unroll
          for (int nj = 0; nj < 4; ++nj){
            int n = n0 + wn*64 + nj*16 + cn;
            outstore[(size_t)row*Nld + n] = acc[mi][nj][rr2] + preadd[(size_t)(row & 31)*spa + n];
          }
        }
      }
  } else {
    #pragma unroll
    for (int mi = 0; mi < 4; ++mi)
      #pragma unroll
      for (int rr2 = 0; rr2 < 4; ++rr2){
        int row = m0 + wm*64 + mi*16 + g*4 + rr2;
        int bb = row & 31;
        float part = 0.f;
        #pragma unroll
        for (int nj = 0; nj < 4; ++nj){
          int n = n0 + wn*64 + nj*16 + cn;
          float tv = ftanh(acc[mi][nj][rr2] + preadd[(size_t)bb*spa + n]);
          part = fmaf(tv, dotw[(size_t)bb*sdw + n], part);
        }
        part += __shfl_xor(part, 1);
        part += __shfl_xor(part, 2);
        part += __shfl_xor(part, 4);
        part += __shfl_xor(part, 8);
        if (cn == 0){
          int l = row >> 5;
          if (!skipedge || (l > 0 && l < Ldot - 1))
            atomicAdd(&dotout[(size_t)bb*Ldot + l], part);
        }
      }
  }
}

// ---------- attention softmax over L per b ----------
__global__ void k_softmax_attn(const float* __restrict__ scores, const int* __restrict__ mask,
                               float* __restrict__ attnw){
  int b = blockIdx.x, t = threadIdx.x;
  __shared__ float red[256];
  float v0 = scores[b*512 + t];
  float v1 = scores[b*512 + 256 + t];
  if (mask[b*512 + t] == 0) v0 = NEGF;
  if (mask[b*512 + 256 + t] == 0) v1 = NEGF;
  red[t] = fmaxf(v0, v1); __syncthreads();
  for (int s = 128; s > 0; s >>= 1){ if (t < s) red[t] = fmaxf(red[t], red[t+s]); __syncthreads(); }
  float mx = red[0]; __syncthreads();
  float e0 = __expf(v0 - mx), e1 = __expf(v1 - mx);
  red[t] = e0 + e1; __syncthreads();
  for (int s = 128; s > 0; s >>= 1){ if (t < s) red[t] += red[t+s]; __syncthreads(); }
  float inv = 1.f / red[0];
  attnw[b*512 + t] = e0 * inv;
  attnw[b*512 + 256 + t] = e1 * inv;
}

// ---------- attentive & selective reads (2-way l-split, 512 thr) ----------
__global__ void k_reads(const u16* __restrict__ encbf, const float* __restrict__ attnw,
                        const float* __restrict__ selp,
                        u16* __restrict__ xbf, u16* __restrict__ genbf){
  int b = blockIdx.y;
  int tid = threadIdx.x;
  int h = blockIdx.x*256 + (tid & 255);
  int lh = tid >> 8;
  float aa = 0.f, as = 0.f;
  int l0 = lh*256, l1 = l0 + 256;
  #pragma unroll 4
  for (int l = l0; l < l1; ++l){
    float e = bf2f(encbf[((size_t)l*32 + b)*1024 + h]);
    aa = fmaf(attnw[b*512 + l], e, aa);
    if (l >= 1 && l < 511) as = fmaf(selp[b*512 + l], e, as);
  }
  __shared__ float red[512][2];
  red[tid][0] = aa; red[tid][1] = as;
  __syncthreads();
  if (tid < 256){
    aa = red[tid][0] + red[tid+256][0];
    as = red[tid][1] + red[tid+256][1];
    u16 ab = f2bf(aa);
    xbf[b*2560 + 512 + h]    = ab;
    xbf[b*2560 + 1536 + h]   = f2bf(as);
    genbf[b*2560 + 1024 + h] = ab;
  }
}

// ---------- fused-convert MFMA GEMM: out[b][o] = bias + sum_k W[o][k]*x[b][k] ----------
// Pipelined: top __syncthreads drains period-old loads; c+1 A-regs + B-GLDS
// (double-buffered Bs) issued right after; pack->compute barrier is raw
// s_barrier + lgkmcnt(0) only, so c+1 loads stay in flight across it.
__launch_bounds__(256)
__global__ void k_wgemm(const float* __restrict__ W1, const u16* __restrict__ xb1, int K1,
                        const float* __restrict__ W2, const u16* __restrict__ xb2, int K2,
                        const float* __restrict__ bias1, const float* __restrict__ bias2,
                        float* __restrict__ outB, int ldo, int cps)
{
  __shared__ u16 As[64*64];      // 8KB, rows of 128B, (row&7) xor-swizzled
  __shared__ u16 Bs[2][32*64];   // 4KB each
  const int tid = threadIdx.x, lane = tid & 63, w = tid >> 6;
  const int o0 = blockIdx.x * 64;
  const int c1 = K1 >> 6;
  const int c0 = blockIdx.y * cps;

  f32x4 acc[2];
  acc[0] = (f32x4){0.f,0.f,0.f,0.f};
  acc[1] = (f32x4){0.f,0.f,0.f,0.f};

  const int ar = tid >> 2, akq = (tid & 3) * 16;   // A: row, k-offset (floats)
  const int aswz = (ar & 7) << 4;
  const int brow = tid >> 3, pslot = tid & 7;
  const int lslot = pslot ^ (brow & 7);            // pre-swizzled B source slot

  float4 aA[4], aB[4];

  auto aload = [&](int c, float4* dst){
    const float* Wp; int Kp, kc;
    if (c < c1){ Wp = W1; Kp = K1; kc = c << 6; }
    else       { Wp = W2; Kp = K2; kc = (c - c1) << 6; }
    const float4* p = (const float4*)(Wp + (size_t)(o0 + ar)*Kp + kc + akq);
    dst[0] = p[0]; dst[1] = p[1]; dst[2] = p[2]; dst[3] = p[3];
  };
  auto bstage = [&](int c, u16* bsb){
    const u16* xp; int Kp, kc;
    if (c < c1){ xp = xb1; Kp = K1; kc = c << 6; }
    else       { xp = xb2; Kp = K2; kc = (c - c1) << 6; }
    GLDS16(xp + (size_t)brow*Kp + kc + lslot*8, (char*)bsb + tid*16);
  };

  auto body = [&](int c, float4* cur, float4* nxt, const u16* bsCur, u16* bsNxt, bool more){
    __syncthreads();   // protects As reuse; drains aload(c)/bstage(c) (1 period old)
    // issue next-chunk loads first — maximum age at next syncthreads
    if (more){ aload(c + 1, nxt); bstage(c + 1, bsNxt); }
    // A pack + swizzled ds_write (regs of c were drained by syncthreads)
    u32 p0 = (u32)f2bf(cur[0].x) | ((u32)f2bf(cur[0].y) << 16);
    u32 p1 = (u32)f2bf(cur[0].z) | ((u32)f2bf(cur[0].w) << 16);
    u32 p2 = (u32)f2bf(cur[1].x) | ((u32)f2bf(cur[1].y) << 16);
    u32 p3 = (u32)f2bf(cur[1].z) | ((u32)f2bf(cur[1].w) << 16);
    u32 p4 = (u32)f2bf(cur[2].x) | ((u32)f2bf(cur[2].y) << 16);
    u32 p5 = (u32)f2bf(cur[2].z) | ((u32)f2bf(cur[2].w) << 16);
    u32 p6 = (u32)f2bf(cur[3].x) | ((u32)f2bf(cur[3].y) << 16);
    u32 p7 = (u32)f2bf(cur[3].z) | ((u32)f2bf(cur[3].w) << 16);
    char* rowp = (char*)As + ar*128;
    *(uint4*)(rowp + ((akq*2)      ^ aswz)) = make_uint4(p0,p1,p2,p3);
    *(uint4*)(rowp + ((akq*2 + 16) ^ aswz)) = make_uint4(p4,p5,p6,p7);
    // ds_writes visible; Bs[c] was certified by the syncthreads above.
    // Raw barrier: do NOT drain vmcnt (c+1 loads in flight).
    asm volatile("s_waitcnt lgkmcnt(0)" ::: "memory");
    __builtin_amdgcn_s_barrier();
    #pragma unroll
    for (int kk = 0; kk < 2; ++kk){
      int rrA = w*16 + (lane & 15);
      int kb  = kk*64 + ((lane >> 4) << 4);
      short8 af = *(const short8*)((const char*)As + rrA*128 + (kb ^ ((rrA & 7) << 4)));
      #pragma unroll
      for (int nj = 0; nj < 2; ++nj){
        int rrB = nj*16 + (lane & 15);
        short8 bfv = *(const short8*)((const char*)bsCur + rrB*128 + (kb ^ ((rrB & 7) << 4)));
        acc[nj] = __builtin_amdgcn_mfma_f32_16x16x32_bf16(af, bfv, acc[nj], 0, 0, 0);
      }
    }
  };

  aload(c0, aA); bstage(c0, Bs[0]);
  for (int li = 0; li < cps; li += 2){          // cps is always even
    body(c0 + li,     aA, aB, Bs[0], Bs[1], true);
    body(c0 + li + 1, aB, aA, Bs[1], Bs[0], (li + 2) < cps);
  }

  // epilogue
  int g = lane >> 4, cn = lane & 15;
  int ob = o0 + w*16 + g*4;
  float* outP = outB + (size_t)blockIdx.y * 32 * (size_t)ldo;
  float4 badd = make_float4(0.f,0.f,0.f,0.f);
  if (blockIdx.y == 0){
    if (bias1){ float4 t = *(const float4*)(bias1 + ob);
      badd.x += t.x; badd.y += t.y; badd.z += t.z; badd.w += t.w; }
    if (bias2){ float4 t = *(const float4*)(bias2 + ob);
      badd.x += t.x; badd.y += t.y; badd.z += t.z; badd.w += t.w; }
  }
  #pragma unroll
  for (int nj = 0; nj < 2; ++nj){
    int bcol = nj*16 + cn;
    float4 v = make_float4(acc[nj][0] + badd.x, acc[nj][1] + badd.y,
                           acc[nj][2] + badd.z, acc[nj][3] + badd.w);
    *(float4*)(outP + (size_t)bcol*ldo + ob) = v;
  }
}

// ---------- LSTM cell, fused 4-part split-K reduce ----------
__global__ void k_cell(const float* __restrict__ gpart, const float* __restrict__ c_in,
                       float* __restrict__ h_out, float* __restrict__ c_out,
                       u16* __restrict__ hbf, int hld, float* __restrict__ h_plain){
  int idx = blockIdx.x*256 + threadIdx.x;
  int b = idx >> 10, j = idx & 1023;
  float gi = 0.f, gf = 0.f, gg = 0.f, go = 0.f;
  #pragma unroll
  for (int p = 0; p < 4; ++p){
    const float* gb = gpart + (size_t)p*131072 + (size_t)b*4096;
    gi += gb[j];
    gf += gb[1024 + j];
    gg += gb[2048 + j];
    go += gb[3072 + j];
  }
  float cv = c_in[b*1024 + j];
  float cnv = fsig(gf)*cv + fsig(gi)*ftanh(gg);
  float hn  = fsig(go)*ftanh(cnv);
  c_out[b*1024 + j] = cnv;
  h_out[b*1024 + j] = hn;
  hbf[(size_t)b*hld + j] = f2bf(hn);
  if (h_plain) h_plain[b*1024 + j] = hn;
}

// ---------- preds tail zero ----------
__global__ void k_zerotail(float* __restrict__ preds){
  int i = blockIdx.x*256 + threadIdx.x;          // 32 * 7000 float4
  if (i < 224000){
    int b = i / 7000, t = i % 7000;
    ((float4*)(preds + (size_t)b*CPY + OUTD))[t] = make_float4(0.f, 0.f, 0.f, 0.f);
  }
}

// ---------- copy-scores finalize + tag init (fused) ----------
__global__ void k_cstag(const float* __restrict__ csacc, const int* __restrict__ mask,
                        const int* __restrict__ src, const int* __restrict__ s2c,
                        float* __restrict__ cs_out, int* __restrict__ tag){
  int i = blockIdx.x*256 + threadIdx.x;
  if (i < 16320){
    int b = i / 510, j = i % 510, l = j + 1;
    cs_out[b*510 + j] = (mask[b*512 + l] != 0) ? csacc[b*512 + l] : NEGF;
    tag[(size_t)b*CPY + s2c[src[(j+1)*32 + b]]] = -1;
  }
}
__global__ void k_tag_max(const int* __restrict__ src, const int* __restrict__ s2c,
                          int* __restrict__ tag){
  int i = blockIdx.x*256 + threadIdx.x;
  if (i < 16320){
    int b = i / 510, j = i % 510;
    atomicMax(&tag[(size_t)b*CPY + s2c[src[(j+1)*32 + b]]], j);
  }
}
__global__ void k_tag_write(const int* __restrict__ src, const int* __restrict__ s2c,
                            const int* __restrict__ tag, const float* __restrict__ cs,
                            float* __restrict__ preds){
  int i = blockIdx.x*256 + threadIdx.x;
  if (i < 16320){
    int b = i / 510, j = i % 510;
    int idx = s2c[src[(j+1)*32 + b]];
    if (tag[(size_t)b*CPY + idx] == j)
      preds[(size_t)b*CPY + idx] = cs[b*510 + j];
  }
}

extern "C" void kernel_launch(void* const* d_in, const int* in_sizes, int n_in,
                              void* d_out, int out_size, void* d_ws, size_t ws_size,
                              hipStream_t stream){
  const int*   src    = (const int*)  d_in[0];
  const int*   inp    = (const int*)  d_in[1];
  const float* hidden = (const float*)d_in[2];
  const float* cst    = (const float*)d_in[3];
  const float* enc    = (const float*)d_in[4];
  const int*   mask   = (const int*)  d_in[5];
  const float* selw   = (const float*)d_in[6];
  const int*   s2c    = (const int*)  d_in[7];
  const float* emb    = (const float*)d_in[8];
  const float* W_attn = (const float*)d_in[9];
  const float* b_attn = (const float*)d_in[10];
  const float* v_attn = (const float*)d_in[11];
  const float* W_ih0  = (const float*)d_in[12];
  const float* W_hh0  = (const float*)d_in[13];
  const float* b_ih0  = (const float*)d_in[14];
  const float* b_hh0  = (const float*)d_in[15];
  const float* W_ih1  = (const float*)d_in[16];
  const float* W_hh1  = (const float*)d_in[17];
  const float* b_ih1  = (const float*)d_in[18];
  const float* b_hh1  = (const float*)d_in[19];
  const float* W_fc   = (const float*)d_in[20];
  const float* b_fc   = (const float*)d_in[21];
  const float* W_copy = (const float*)d_in[22];
  const float* b_copy = (const float*)d_in[23];

  if (ws_size < WS_TOTAL) return;

  float* out = (float*)d_out;
  char*  ws  = (char*)d_ws;
  u16*   encbf  = (u16*)  (ws + WS_ENC);
  u16*   wa1t   = (u16*)  (ws + WS_WA1T);
  u16*   wa2t   = (u16*)  (ws + WS_WA2T);
  u16*   wct    = (u16*)  (ws + WS_WCT);
  float* hpf    = (float*)(ws + WS_HPF);
  float* scores = (float*)(ws + WS_SCORES);
  float* csacc  = (float*)(ws + WS_CSACC);
  float* selp   = (float*)(ws + WS_SELP);
  u16*   xbf    = (u16*)  (ws + WS_XBF);
  u16*   genbf  = (u16*)  (ws + WS_GENBF);
  u16*   h0pbf  = (u16*)  (ws + WS_H0PBF);
  u16*   h1pbf  = (u16*)  (ws + WS_H1PBF);
  u16*   h0nbf  = (u16*)  (ws + WS_H0NBF);
  float* gpart  = (float*)(ws + WS_GPART);
  float* h1     = (float*)(ws + WS_H1);
  int*   tag    = (int*)  (ws + WS_TAG);

  // converts / transposes / prep
  k_f32_to_bf16<<<2048, 256, 0, stream>>>(enc,    encbf, (LL*BB*H2)/4);
  k_f32_to_bf16<<<512,  256, 0, stream>>>(W_copy, wct,   (DH*H2)/4);
  k_wattn_t<<<dim3(16, 32), 256, 0, stream>>>(W_attn, wa1t, wa2t);
  k_prep<<<32, 256, 0, stream>>>(src, inp, hidden, selw, s2c, emb, mask,
                                 xbf, genbf, h0pbf, h1pbf, scores, csacc, selp);

  // h-part: hpf[b][n] = b_attn[n] + h_top @ Wa1
  k_mfma<<<8, 256, 0, stream>>>(h1pbf, 1024, 32, wa1t, 1024, 1024,
                                b_attn, 0, nullptr, 0, nullptr, 512, 0, hpf, 8);
  // attention scores
  k_mfma<<<1024, 256, 0, stream>>>(encbf, 1024, LL*BB, wa2t, 1024, 1024,
                                   hpf, 1024, v_attn, 0, scores, 512, 0, nullptr, 8);
  k_softmax_attn<<<32, 256, 0, stream>>>(scores, mask, out + ATTN_OFF);
  k_reads<<<dim3(4, 32), 512, 0, stream>>>(encbf, out + ATTN_OFF, selp, xbf, genbf);

  // LSTM layer 0 gates (split-K=4, 56 chunks -> 14/part)
  k_wgemm<<<dim3(64, 4), 256, 0, stream>>>(W_ih0, xbf, KX, W_hh0, h0pbf, DH,
                                           b_ih0, b_hh0, gpart, 4096, 14);
  k_cell<<<128, 256, 0, stream>>>(gpart, cst, out + HID_OFF, out + C_OFF,
                                  h0nbf, 1024, nullptr);
  // LSTM layer 1 gates (32 chunks -> 8/part)
  k_wgemm<<<dim3(64, 4), 256, 0, stream>>>(W_ih1, h0nbf, DH, W_hh1, h1pbf, DH,
                                           b_ih1, b_hh1, gpart, 4096, 8);
  k_cell<<<128, 256, 0, stream>>>(gpart, cst + 32768, out + HID_OFF + 32768,
                                  out + C_OFF + 32768, genbf, 2560, h1);

  // copy scores (needs h1, encbf)
  k_mfma<<<1024, 256, 0, stream>>>(encbf, 1024, LL*BB, wct, 1024, 1024,
                                   b_copy, 0, h1, 1024, csacc, 512, 1, nullptr, 8);

  // generator -> preds[:, :32000]  (40 chunks, no split)
  k_wgemm<<<dim3(500, 1), 256, 0, stream>>>(W_fc, genbf, KX, nullptr, nullptr, 0,
                                            b_fc, nullptr, out, CPY, 40);
  k_zerotail<<<875, 256, 0, stream>>>(out);

  // scatter (last-wins)
  k_cstag   <<<64, 256, 0, stream>>>(csacc, mask, src, s2c, out + CS_OFF, tag);
  k_tag_max <<<64, 256, 0, stream>>>(src, s2c, tag);
  k_tag_write<<<64, 256, 0, stream>>>(src, s2c, tag, out + CS_OFF, out);
}

// Round 6
// 378.784 us; speedup vs baseline: 2.3613x; 1.0444x over previous
//
#include <hip/hip_runtime.h>
#include <stdint.h>

typedef unsigned short u16;
typedef unsigned int   u32;
typedef __attribute__((ext_vector_type(8))) short short8;
typedef __attribute__((ext_vector_type(4))) float f32x4;

#define NEGF (-1.0e10f)

// ---------- sizes ----------
static constexpr int LL = 512, BB = 32, EE = 512, H2 = 1024, DH = 1024;
static constexpr int KX = 2560, OUTD = 32000, CPY = 60000;

// ---------- output offsets (floats) ----------
static constexpr size_t HID_OFF   = 1920000;              // 2*32*1024
static constexpr size_t C_OFF     = HID_OFF + 65536;
static constexpr size_t ATTN_OFF  = C_OFF + 65536;        // 32*512
static constexpr size_t CS_OFF    = ATTN_OFF + 16384;     // 32*510

// ---------- workspace offsets (bytes) ----------
static constexpr size_t WS_ENC    = 0;                     // 16384*1024*2 = 33.5MB
static constexpr size_t WS_WA1T   = 33554432;              // 1024*1024*2
static constexpr size_t WS_WA2T   = 35651584;
static constexpr size_t WS_WCT    = 37748736;
static constexpr size_t WS_HPF    = 39845888;              // 32*1024*4
static constexpr size_t WS_SCORES = 39976960;              // 32*512*4
static constexpr size_t WS_SELP   = 40108032;
static constexpr size_t WS_XBF    = 40173568;              // 32*2560*2
static constexpr size_t WS_GENBF  = 40337408;              // 32*2560*2
static constexpr size_t WS_H0PBF  = 40501248;              // 32*1024*2
static constexpr size_t WS_H1PBF  = 40566784;              // 32*1024*2
static constexpr size_t WS_H0NBF  = 40632320;              // 32*1024*2
static constexpr size_t WS_PROJ   = 50331648;              // 16384*1024*2 = 33.5MB
static constexpr size_t WS_TOTAL  = WS_PROJ + 33554432;
// aliased (stream-order safe):
static constexpr size_t WS_GPART  = WS_WA1T;               // 8*32*4096*4 = 4MB (wa1t+wa2t dead after k_mfma2)
static constexpr size_t WS_TAG    = WS_ENC;                // 32*60000*4 (encbf dead after k_reads)

// ---------- helpers ----------
__device__ __forceinline__ u16 f2bf(float x){
  u32 u = __builtin_bit_cast(u32, x);
  u32 r = (u + 0x7FFFu + ((u >> 16) & 1u)) >> 16;
  return (u16)r;
}
__device__ __forceinline__ float bf2f(u16 h){
  u32 u = ((u32)h) << 16; return __builtin_bit_cast(float, u);
}
__device__ __forceinline__ float fsig(float x){ return 1.f/(1.f + __expf(-x)); }
__device__ __forceinline__ float ftanh(float x){
  float e = __expf(2.f*x);
  return 1.f - 2.f/(e + 1.f);
}

#define GLDS16(gp, lp) __builtin_amdgcn_global_load_lds( \
    (__attribute__((address_space(1))) void*)(gp), \
    (__attribute__((address_space(3))) void*)(lp), 16, 0, 0)

// ---------- f32 -> bf16 elementwise ----------
__global__ void k_f32_to_bf16(const float* __restrict__ in, u16* __restrict__ out, int n4){
  int stride = gridDim.x * blockDim.x;
  for (int i = blockIdx.x*blockDim.x + threadIdx.x; i < n4; i += stride){
    float4 v = ((const float4*)in)[i];
    u32 lo = (u32)f2bf(v.x) | ((u32)f2bf(v.y) << 16);
    u32 hi = (u32)f2bf(v.z) | ((u32)f2bf(v.w) << 16);
    ((uint2*)out)[i] = make_uint2(lo, hi);
  }
}

// ---------- transpose W_attn (2048k x 1024n) -> Wa1T/Wa2T [n][k] bf16 ----------
__global__ void k_wattn_t(const float* __restrict__ W, u16* __restrict__ wa1t, u16* __restrict__ wa2t){
  __shared__ float Tt[64*65];
  int n0 = blockIdx.x*64, k0 = blockIdx.y*64;
  int t = threadIdx.x;
  int nn = t & 63, kq = t >> 6;
  for (int kk = kq; kk < 64; kk += 4)
    Tt[kk*65 + nn] = W[(size_t)(k0+kk)*1024 + n0 + nn];
  __syncthreads();
  u16* dst = (k0 < 1024) ? wa1t : wa2t;
  int kbase = (k0 < 1024) ? k0 : (k0 - 1024);
  int kk2 = t & 63, nq = t >> 6;
  for (int nn2 = nq; nn2 < 64; nn2 += 4)
    dst[(size_t)(n0+nn2)*1024 + kbase + kk2] = f2bf(Tt[kk2*65 + nn2]);
}

// ---------- prep: embedded, prev-h bf16, zero scores, sel softmax ----------
__global__ void k_prep(const int* __restrict__ src, const int* __restrict__ inp,
                       const float* __restrict__ hidden, const float* __restrict__ selw,
                       const int* __restrict__ s2c, const float* __restrict__ emb,
                       const int* __restrict__ mask,
                       u16* __restrict__ xbf, u16* __restrict__ genbf,
                       u16* __restrict__ h0pbf, u16* __restrict__ h1pbf,
                       float* __restrict__ scores, float* __restrict__ selp)
{
  int b = blockIdx.x, t = threadIdx.x;
  int ib = inp[b];
  for (int h = t; h < 512; h += 256){
    u16 e = f2bf(emb[(size_t)ib*512 + h]);
    xbf[b*2560 + h] = e;              // x = [emb, att, sel]
    genbf[b*2560 + 2048 + h] = e;     // gen = [h1, att, emb]
  }
  for (int k = t; k < 1024; k += 256){
    h0pbf[b*1024 + k] = f2bf(hidden[b*1024 + k]);
    h1pbf[b*1024 + k] = f2bf(hidden[32768 + b*1024 + k]);
  }
  for (int l = t; l < 512; l += 256)
    scores[b*512 + l] = 0.f;
  __shared__ float red[256];
  float lg[2];
  #pragma unroll
  for (int i = 0; i < 2; ++i){
    int j = t + i*256;
    lg[i] = NEGF;
    if (j < 510){
      int cs = s2c[src[(j+1)*32 + b]];
      if (cs == ib) lg[i] = selw[b*510 + j];
    }
  }
  red[t] = fmaxf(lg[0], lg[1]); __syncthreads();
  for (int s = 128; s > 0; s >>= 1){ if (t < s) red[t] = fmaxf(red[t], red[t+s]); __syncthreads(); }
  float mx = red[0]; __syncthreads();
  float e0 = (t < 510)     ? __expf(lg[0] - mx) : 0.f;
  float e1 = (t+256 < 510) ? __expf(lg[1] - mx) : 0.f;
  red[t] = e0 + e1; __syncthreads();
  for (int s = 128; s > 0; s >>= 1){ if (t < s) red[t] += red[t+s]; __syncthreads(); }
  float inv = 1.f / red[0];
  #pragma unroll
  for (int i = 0; i < 2; ++i){
    int j = t + i*256;
    if (j < 510){
      float v = ((i == 0) ? e0 : e1) * inv;
      int l = j + 1;
      selp[b*512 + l] = (mask[b*512 + l] != 0) ? v : NEGF;
    }
  }
}

// ---------- bf16 MFMA GEMM, 128x128 tile, BK=32, dbuf (hpf only now) ----------
__launch_bounds__(256)
__global__ void k_mfma(const u16* __restrict__ A, int lda, int Mvalid,
                       const u16* __restrict__ Bmat, int ldb, int K,
                       const float* __restrict__ preadd, int spa,
                       float* __restrict__ outstore, int NT)
{
  __shared__ u16 As[2][128*32];
  __shared__ u16 Bs[2][128*32];
  int wg = blockIdx.x;
  int mt = wg / NT, nt = wg % NT;
  int m0 = mt * 128, n0 = nt * 128;
  int tid = threadIdx.x, lane = tid & 63, wid = tid >> 6;
  int wm = wid >> 1, wn = wid & 1;

  f32x4 acc[4][4];
  #pragma unroll
  for (int i = 0; i < 4; ++i)
    #pragma unroll
    for (int j = 0; j < 4; ++j)
      acc[i][j] = (f32x4){0.f, 0.f, 0.f, 0.f};

  int r0 = tid >> 2,          s0 = tid & 3;
  int r1 = (tid + 256) >> 2;
  int xv0 = (r0 ^ (r0 >> 2)) & 3, xv1 = (r1 ^ (r1 >> 2)) & 3;
  int sc0 = (s0 ^ xv0) << 3,      sc1 = (s0 ^ xv1) << 3;
  int raA0 = m0 + r0; if (raA0 >= Mvalid) raA0 = Mvalid - 1;
  int raA1 = m0 + r1; if (raA1 >= Mvalid) raA1 = Mvalid - 1;
  int rbB0 = n0 + r0, rbB1 = n0 + r1;

  auto stage = [&](int k0, u16* asb, u16* bsb){
    GLDS16(A    + (size_t)raA0*lda + k0 + sc0, (char*)asb + tid*16);
    GLDS16(A    + (size_t)raA1*lda + k0 + sc1, (char*)asb + (tid+256)*16);
    GLDS16(Bmat + (size_t)rbB0*ldb + k0 + sc0, (char*)bsb + tid*16);
    GLDS16(Bmat + (size_t)rbB1*ldb + k0 + sc1, (char*)bsb + (tid+256)*16);
  };

  int KT = K >> 5;
  stage(0, As[0], Bs[0]);
  for (int kt = 0; kt < KT; ++kt){
    __syncthreads();
    if (kt + 1 < KT) stage((kt+1) << 5, As[(kt+1) & 1], Bs[(kt+1) & 1]);
    const char* ap = (const char*)As[kt & 1];
    const char* bp = (const char*)Bs[kt & 1];
    short8 af[4], bfr[4];
    #pragma unroll
    for (int mi = 0; mi < 4; ++mi){
      int rr = wm*64 + mi*16 + (lane & 15);
      int xv = (rr ^ (rr >> 2)) & 3;
      af[mi] = *(const short8*)(ap + rr*64 + (((lane >> 4) ^ xv) << 4));
    }
    #pragma unroll
    for (int nj = 0; nj < 4; ++nj){
      int rr = wn*64 + nj*16 + (lane & 15);
      int xv = (rr ^ (rr >> 2)) & 3;
      bfr[nj] = *(const short8*)(bp + rr*64 + (((lane >> 4) ^ xv) << 4));
    }
    #pragma unroll
    for (int mi = 0; mi < 4; ++mi)
      #pragma unroll
      for (int nj = 0; nj < 4; ++nj)
        acc[mi][nj] = __builtin_amdgcn_mfma_f32_16x16x32_bf16(af[mi], bfr[nj], acc[mi][nj], 0, 0, 0);
  }

  int g = lane >> 4, cn = lane & 15;
  int Nld = NT * 128;
  #pragma unroll
  for (int mi = 0; mi < 4; ++mi)
    #pragma unroll
    for (int rr2 = 0; rr2 < 4; ++rr2){
      int row = m0 + wm*64 + mi*16 + g*4 + rr2;
      if (row < Mvalid){
        #pragma unroll
        for (int nj = 0; nj < 4; ++nj){
          int n = n0 + wn*64 + nj*16 + cn;
          outstore[(size_t)row*Nld + n] = acc[mi][nj][rr2] + preadd[(size_t)(row & 31)*spa + n];
        }
      }
    }
}

// ---------- FUSED dual-B enc GEMM: attention scores + copy proj ----------
// A = encbf (16384x1024). B1 = wa2t -> tanh(acc+hpf) . v_attn -> scores (atomic).
// B2 = wct  -> tanh(acc+b_copy) -> projbf (bf16). A staged ONCE for both.
__launch_bounds__(256, 2)
__global__ void k_mfma2(const u16* __restrict__ A, const u16* __restrict__ B1,
                        const u16* __restrict__ B2, const float* __restrict__ hpf,
                        const float* __restrict__ vattn, const float* __restrict__ bcopy,
                        float* __restrict__ scores, u16* __restrict__ projbf)
{
  __shared__ u16 As [2][128*32];
  __shared__ u16 B1s[2][128*32];
  __shared__ u16 B2s[2][128*32];
  const int lda = 1024;
  int nwg = gridDim.x, bid = blockIdx.x;
  int q = nwg >> 3, r = nwg & 7, xc = bid & 7, ix = bid >> 3;
  int wg = (xc < r ? xc*(q+1) : r*(q+1) + (xc - r)*q) + ix;   // bijective XCD swizzle
  int mt = wg >> 3, nt = wg & 7;                              // NT = 8
  int m0 = mt * 128, n0 = nt * 128;
  int tid = threadIdx.x, lane = tid & 63, wid = tid >> 6;
  int wm = wid >> 1, wn = wid & 1;

  f32x4 acc1[4][4], acc2[4][4];
  #pragma unroll
  for (int i = 0; i < 4; ++i)
    #pragma unroll
    for (int j = 0; j < 4; ++j){
      acc1[i][j] = (f32x4){0.f,0.f,0.f,0.f};
      acc2[i][j] = (f32x4){0.f,0.f,0.f,0.f};
    }

  int r0 = tid >> 2,          s0 = tid & 3;
  int r1 = (tid + 256) >> 2;
  int xv0 = (r0 ^ (r0 >> 2)) & 3, xv1 = (r1 ^ (r1 >> 2)) & 3;
  int sc0 = (s0 ^ xv0) << 3,      sc1 = (s0 ^ xv1) << 3;
  size_t a0 = (size_t)(m0 + r0)*lda, a1 = (size_t)(m0 + r1)*lda;
  size_t b0 = (size_t)(n0 + r0)*lda, b1o = (size_t)(n0 + r1)*lda;

  auto stage = [&](int k0, int buf){
    GLDS16(A  + a0  + k0 + sc0, (char*)As [buf] + tid*16);
    GLDS16(A  + a1  + k0 + sc1, (char*)As [buf] + (tid+256)*16);
    GLDS16(B1 + b0  + k0 + sc0, (char*)B1s[buf] + tid*16);
    GLDS16(B1 + b1o + k0 + sc1, (char*)B1s[buf] + (tid+256)*16);
    GLDS16(B2 + b0  + k0 + sc0, (char*)B2s[buf] + tid*16);
    GLDS16(B2 + b1o + k0 + sc1, (char*)B2s[buf] + (tid+256)*16);
  };

  stage(0, 0);
  for (int kt = 0; kt < 32; ++kt){
    __syncthreads();
    if (kt + 1 < 32) stage((kt+1) << 5, (kt+1) & 1);
    const char* ap  = (const char*)As [kt & 1];
    const char* b1p = (const char*)B1s[kt & 1];
    const char* b2p = (const char*)B2s[kt & 1];
    short8 af[4], bfr[4];
    #pragma unroll
    for (int mi = 0; mi < 4; ++mi){
      int rr = wm*64 + mi*16 + (lane & 15);
      int xv = (rr ^ (rr >> 2)) & 3;
      af[mi] = *(const short8*)(ap + rr*64 + (((lane >> 4) ^ xv) << 4));
    }
    #pragma unroll
    for (int nj = 0; nj < 4; ++nj){
      int rr = wn*64 + nj*16 + (lane & 15);
      int xv = (rr ^ (rr >> 2)) & 3;
      bfr[nj] = *(const short8*)(b1p + rr*64 + (((lane >> 4) ^ xv) << 4));
    }
    #pragma unroll
    for (int mi = 0; mi < 4; ++mi)
      #pragma unroll
      for (int nj = 0; nj < 4; ++nj)
        acc1[mi][nj] = __builtin_amdgcn_mfma_f32_16x16x32_bf16(af[mi], bfr[nj], acc1[mi][nj], 0, 0, 0);
    #pragma unroll
    for (int nj = 0; nj < 4; ++nj){
      int rr = wn*64 + nj*16 + (lane & 15);
      int xv = (rr ^ (rr >> 2)) & 3;
      bfr[nj] = *(const short8*)(b2p + rr*64 + (((lane >> 4) ^ xv) << 4));
    }
    #pragma unroll
    for (int mi = 0; mi < 4; ++mi)
      #pragma unroll
      for (int nj = 0; nj < 4; ++nj)
        acc2[mi][nj] = __builtin_amdgcn_mfma_f32_16x16x32_bf16(af[mi], bfr[nj], acc2[mi][nj], 0, 0, 0);
  }

  int g = lane >> 4, cn = lane & 15;
  // B1 epilogue: attention score dot
  #pragma unroll
  for (int mi = 0; mi < 4; ++mi)
    #pragma unroll
    for (int rr2 = 0; rr2 < 4; ++rr2){
      int row = m0 + wm*64 + mi*16 + g*4 + rr2;
      int bb = row & 31;
      float part = 0.f;
      #pragma unroll
      for (int nj = 0; nj < 4; ++nj){
        int n = n0 + wn*64 + nj*16 + cn;
        float tv = ftanh(acc1[mi][nj][rr2] + hpf[(size_t)bb*1024 + n]);
        part = fmaf(tv, vattn[n], part);
      }
      part += __shfl_xor(part, 1);
      part += __shfl_xor(part, 2);
      part += __shfl_xor(part, 4);
      part += __shfl_xor(part, 8);
      if (cn == 0) atomicAdd(&scores[(size_t)bb*512 + (row >> 5)], part);
    }
  // B2 epilogue: proj store (bf16)
  #pragma unroll
  for (int mi = 0; mi < 4; ++mi)
    #pragma unroll
    for (int rr2 = 0; rr2 < 4; ++rr2){
      int row = m0 + wm*64 + mi*16 + g*4 + rr2;
      #pragma unroll
      for (int nj = 0; nj < 4; ++nj){
        int n = n0 + wn*64 + nj*16 + cn;
        projbf[(size_t)row*1024 + n] = f2bf(ftanh(acc2[mi][nj][rr2] + bcopy[n]));
      }
    }
}

// ---------- attention softmax over L per b ----------
__global__ void k_softmax_attn(const float* __restrict__ scores, const int* __restrict__ mask,
                               float* __restrict__ attnw){
  int b = blockIdx.x, t = threadIdx.x;
  __shared__ float red[256];
  float v0 = scores[b*512 + t];
  float v1 = scores[b*512 + 256 + t];
  if (mask[b*512 + t] == 0) v0 = NEGF;
  if (mask[b*512 + 256 + t] == 0) v1 = NEGF;
  red[t] = fmaxf(v0, v1); __syncthreads();
  for (int s = 128; s > 0; s >>= 1){ if (t < s) red[t] = fmaxf(red[t], red[t+s]); __syncthreads(); }
  float mx = red[0]; __syncthreads();
  float e0 = __expf(v0 - mx), e1 = __expf(v1 - mx);
  red[t] = e0 + e1; __syncthreads();
  for (int s = 128; s > 0; s >>= 1){ if (t < s) red[t] += red[t+s]; __syncthreads(); }
  float inv = 1.f / red[0];
  attnw[b*512 + t] = e0 * inv;
  attnw[b*512 + 256 + t] = e1 * inv;
}

// ---------- attentive & selective reads (2-way l-split, 512 thr) ----------
__global__ void k_reads(const u16* __restrict__ encbf, const float* __restrict__ attnw,
                        const float* __restrict__ selp,
                        u16* __restrict__ xbf, u16* __restrict__ genbf){
  int b = blockIdx.y;
  int tid = threadIdx.x;
  int h = blockIdx.x*256 + (tid & 255);
  int lh = tid >> 8;
  float aa = 0.f, as = 0.f;
  int l0 = lh*256, l1 = l0 + 256;
  #pragma unroll 4
  for (int l = l0; l < l1; ++l){
    float e = bf2f(encbf[((size_t)l*32 + b)*1024 + h]);
    aa = fmaf(attnw[b*512 + l], e, aa);
    if (l >= 1 && l < 511) as = fmaf(selp[b*512 + l], e, as);
  }
  __shared__ float red[512][2];
  red[tid][0] = aa; red[tid][1] = as;
  __syncthreads();
  if (tid < 256){
    aa = red[tid][0] + red[tid+256][0];
    as = red[tid][1] + red[tid+256][1];
    u16 ab = f2bf(aa);
    xbf[b*2560 + 512 + h]    = ab;
    xbf[b*2560 + 1536 + h]   = f2bf(as);
    genbf[b*2560 + 1024 + h] = ab;
  }
}

// ---------- fused-convert MFMA GEMM: out[b][o] = bias + sum_k W[o][k]*x[b][k] ----------
__launch_bounds__(256)
__global__ void k_wgemm(const float* __restrict__ W1, const u16* __restrict__ xb1, int K1,
                        const float* __restrict__ W2, const u16* __restrict__ xb2, int K2,
                        const float* __restrict__ bias1, const float* __restrict__ bias2,
                        float* __restrict__ outB, int ldo, int cps)
{
  __shared__ u16 As[64*64];      // 8KB, rows of 128B, (row&7) xor-swizzled
  __shared__ u16 Bs[2][32*64];   // 4KB each
  const int tid = threadIdx.x, lane = tid & 63, w = tid >> 6;
  const int o0 = blockIdx.x * 64;
  const int c1 = K1 >> 6;
  const int c0 = blockIdx.y * cps;

  f32x4 acc[2];
  acc[0] = (f32x4){0.f,0.f,0.f,0.f};
  acc[1] = (f32x4){0.f,0.f,0.f,0.f};

  const int ar = tid >> 2, akq = (tid & 3) * 16;
  const int aswz = (ar & 7) << 4;
  const int brow = tid >> 3, pslot = tid & 7;
  const int lslot = pslot ^ (brow & 7);

  float4 aA[4], aB[4];

  auto aload = [&](int c, float4* dst){
    const float* Wp; int Kp, kc;
    if (c < c1){ Wp = W1; Kp = K1; kc = c << 6; }
    else       { Wp = W2; Kp = K2; kc = (c - c1) << 6; }
    const float4* p = (const float4*)(Wp + (size_t)(o0 + ar)*Kp + kc + akq);
    dst[0] = p[0]; dst[1] = p[1]; dst[2] = p[2]; dst[3] = p[3];
  };
  auto bstage = [&](int c, u16* bsb){
    const u16* xp; int Kp, kc;
    if (c < c1){ xp = xb1; Kp = K1; kc = c << 6; }
    else       { xp = xb2; Kp = K2; kc = (c - c1) << 6; }
    GLDS16(xp + (size_t)brow*Kp + kc + lslot*8, (char*)bsb + tid*16);
  };

  auto body = [&](int c, float4* cur, float4* nxt, const u16* bsCur, u16* bsNxt, bool more){
    __syncthreads();
    if (more){ aload(c + 1, nxt); bstage(c + 1, bsNxt); }
    u32 p0 = (u32)f2bf(cur[0].x) | ((u32)f2bf(cur[0].y) << 16);
    u32 p1 = (u32)f2bf(cur[0].z) | ((u32)f2bf(cur[0].w) << 16);
    u32 p2 = (u32)f2bf(cur[1].x) | ((u32)f2bf(cur[1].y) << 16);
    u32 p3 = (u32)f2bf(cur[1].z) | ((u32)f2bf(cur[1].w) << 16);
    u32 p4 = (u32)f2bf(cur[2].x) | ((u32)f2bf(cur[2].y) << 16);
    u32 p5 = (u32)f2bf(cur[2].z) | ((u32)f2bf(cur[2].w) << 16);
    u32 p6 = (u32)f2bf(cur[3].x) | ((u32)f2bf(cur[3].y) << 16);
    u32 p7 = (u32)f2bf(cur[3].z) | ((u32)f2bf(cur[3].w) << 16);
    char* rowp = (char*)As + ar*128;
    *(uint4*)(rowp + ((akq*2)      ^ aswz)) = make_uint4(p0,p1,p2,p3);
    *(uint4*)(rowp + ((akq*2 + 16) ^ aswz)) = make_uint4(p4,p5,p6,p7);
    asm volatile("s_waitcnt lgkmcnt(0)" ::: "memory");
    __builtin_amdgcn_s_barrier();
    #pragma unroll
    for (int kk = 0; kk < 2; ++kk){
      int rrA = w*16 + (lane & 15);
      int kb  = kk*64 + ((lane >> 4) << 4);
      short8 af = *(const short8*)((const char*)As + rrA*128 + (kb ^ ((rrA & 7) << 4)));
      #pragma unroll
      for (int nj = 0; nj < 2; ++nj){
        int rrB = nj*16 + (lane & 15);
        short8 bfv = *(const short8*)((const char*)bsCur + rrB*128 + (kb ^ ((rrB & 7) << 4)));
        acc[nj] = __builtin_amdgcn_mfma_f32_16x16x32_bf16(af, bfv, acc[nj], 0, 0, 0);
      }
    }
  };

  aload(c0, aA); bstage(c0, Bs[0]);
  for (int li = 0; li < cps; li += 2){          // cps even
    body(c0 + li,     aA, aB, Bs[0], Bs[1], true);
    body(c0 + li + 1, aB, aA, Bs[1], Bs[0], (li + 2) < cps);
  }

  int g = lane >> 4, cn = lane & 15;
  int ob = o0 + w*16 + g*4;
  float* outP = outB + (size_t)blockIdx.y * 32 * (size_t)ldo;
  float4 badd = make_float4(0.f,0.f,0.f,0.f);
  if (blockIdx.y == 0){
    if (bias1){ float4 t = *(const float4*)(bias1 + ob);
      badd.x += t.x; badd.y += t.y; badd.z += t.z; badd.w += t.w; }
    if (bias2){ float4 t = *(const float4*)(bias2 + ob);
      badd.x += t.x; badd.y += t.y; badd.z += t.z; badd.w += t.w; }
  }
  #pragma unroll
  for (int nj = 0; nj < 2; ++nj){
    int bcol = nj*16 + cn;
    float4 v = make_float4(acc[nj][0] + badd.x, acc[nj][1] + badd.y,
                           acc[nj][2] + badd.z, acc[nj][3] + badd.w);
    *(float4*)(outP + (size_t)bcol*ldo + ob) = v;
  }
}

// ---------- LSTM cell, fused nparts split-K reduce ----------
__global__ void k_cell(const float* __restrict__ gpart, int nparts,
                       const float* __restrict__ c_in,
                       float* __restrict__ h_out, float* __restrict__ c_out,
                       u16* __restrict__ hbf, int hld){
  int idx = blockIdx.x*256 + threadIdx.x;
  int b = idx >> 10, j = idx & 1023;
  float gi = 0.f, gf = 0.f, gg = 0.f, go = 0.f;
  for (int p = 0; p < nparts; ++p){
    const float* gb = gpart + (size_t)p*131072 + (size_t)b*4096;
    gi += gb[j];
    gf += gb[1024 + j];
    gg += gb[2048 + j];
    go += gb[3072 + j];
  }
  float cv = c_in[b*1024 + j];
  float cnv = fsig(gf)*cv + fsig(gi)*ftanh(gg);
  float hn  = fsig(go)*ftanh(cnv);
  c_out[b*1024 + j] = cnv;
  h_out[b*1024 + j] = hn;
  hbf[(size_t)b*hld + j] = f2bf(hn);
}

// ---------- proj . h1 dot -> copy scores (+mask, +tag init) ----------
__global__ void k_pdot(const u16* __restrict__ projbf, const u16* __restrict__ genbf,
                       const int* __restrict__ mask, const int* __restrict__ src,
                       const int* __restrict__ s2c,
                       float* __restrict__ cs_out, int* __restrict__ tag)
{
  int tid = threadIdx.x, lane = tid & 63, w = tid >> 6;
  int row = blockIdx.x*4 + w;                 // 4096 blocks x 4 waves
  int l = row >> 5, b = row & 31;
  const u16* pr = projbf + (size_t)row*1024 + lane*16;
  const u16* hr = genbf  + (size_t)b*2560 + lane*16;
  short8 p0 = *(const short8*)pr,     p1 = *(const short8*)(pr + 8);
  short8 h0 = *(const short8*)hr,     h1 = *(const short8*)(hr + 8);
  float s = 0.f;
  #pragma unroll
  for (int i = 0; i < 8; ++i) s = fmaf(bf2f((u16)p0[i]), bf2f((u16)h0[i]), s);
  #pragma unroll
  for (int i = 0; i < 8; ++i) s = fmaf(bf2f((u16)p1[i]), bf2f((u16)h1[i]), s);
  s += __shfl_xor(s, 1);  s += __shfl_xor(s, 2);  s += __shfl_xor(s, 4);
  s += __shfl_xor(s, 8);  s += __shfl_xor(s, 16); s += __shfl_xor(s, 32);
  if (lane == 0 && l >= 1 && l <= 510){
    int j = l - 1;
    cs_out[b*510 + j] = (mask[b*512 + l] != 0) ? s : NEGF;
    tag[(size_t)b*CPY + s2c[src[l*32 + b]]] = -1;
  }
}

// ---------- preds tail zero ----------
__global__ void k_zerotail(float* __restrict__ preds){
  int i = blockIdx.x*256 + threadIdx.x;          // 32 * 7000 float4
  if (i < 224000){
    int b = i / 7000, t = i % 7000;
    ((float4*)(preds + (size_t)b*CPY + OUTD))[t] = make_float4(0.f, 0.f, 0.f, 0.f);
  }
}

// ---------- scatter passes ----------
__global__ void k_tag_max(const int* __restrict__ src, const int* __restrict__ s2c,
                          int* __restrict__ tag){
  int i = blockIdx.x*256 + threadIdx.x;
  if (i < 16320){
    int b = i / 510, j = i % 510;
    atomicMax(&tag[(size_t)b*CPY + s2c[src[(j+1)*32 + b]]], j);
  }
}
__global__ void k_tag_write(const int* __restrict__ src, const int* __restrict__ s2c,
                            const int* __restrict__ tag, const float* __restrict__ cs,
                            float* __restrict__ preds){
  int i = blockIdx.x*256 + threadIdx.x;
  if (i < 16320){
    int b = i / 510, j = i % 510;
    int idx = s2c[src[(j+1)*32 + b]];
    if (tag[(size_t)b*CPY + idx] == j)
      preds[(size_t)b*CPY + idx] = cs[b*510 + j];
  }
}

extern "C" void kernel_launch(void* const* d_in, const int* in_sizes, int n_in,
                              void* d_out, int out_size, void* d_ws, size_t ws_size,
                              hipStream_t stream){
  const int*   src    = (const int*)  d_in[0];
  const int*   inp    = (const int*)  d_in[1];
  const float* hidden = (const float*)d_in[2];
  const float* cst    = (const float*)d_in[3];
  const float* enc    = (const float*)d_in[4];
  const int*   mask   = (const int*)  d_in[5];
  const float* selw   = (const float*)d_in[6];
  const int*   s2c    = (const int*)  d_in[7];
  const float* emb    = (const float*)d_in[8];
  const float* W_attn = (const float*)d_in[9];
  const float* b_attn = (const float*)d_in[10];
  const float* v_attn = (const float*)d_in[11];
  const float* W_ih0  = (const float*)d_in[12];
  const float* W_hh0  = (const float*)d_in[13];
  const float* b_ih0  = (const float*)d_in[14];
  const float* b_hh0  = (const float*)d_in[15];
  const float* W_ih1  = (const float*)d_in[16];
  const float* W_hh1  = (const float*)d_in[17];
  const float* b_ih1  = (const float*)d_in[18];
  const float* b_hh1  = (const float*)d_in[19];
  const float* W_fc   = (const float*)d_in[20];
  const float* b_fc   = (const float*)d_in[21];
  const float* W_copy = (const float*)d_in[22];
  const float* b_copy = (const float*)d_in[23];

  if (ws_size < WS_TOTAL) return;

  float* out = (float*)d_out;
  char*  ws  = (char*)d_ws;
  u16*   encbf  = (u16*)  (ws + WS_ENC);
  u16*   wa1t   = (u16*)  (ws + WS_WA1T);
  u16*   wa2t   = (u16*)  (ws + WS_WA2T);
  u16*   wct    = (u16*)  (ws + WS_WCT);
  float* hpf    = (float*)(ws + WS_HPF);
  float* scores = (float*)(ws + WS_SCORES);
  float* selp   = (float*)(ws + WS_SELP);
  u16*   xbf    = (u16*)  (ws + WS_XBF);
  u16*   genbf  = (u16*)  (ws + WS_GENBF);
  u16*   h0pbf  = (u16*)  (ws + WS_H0PBF);
  u16*   h1pbf  = (u16*)  (ws + WS_H1PBF);
  u16*   h0nbf  = (u16*)  (ws + WS_H0NBF);
  u16*   projbf = (u16*)  (ws + WS_PROJ);
  float* gpart  = (float*)(ws + WS_GPART);
  int*   tag    = (int*)  (ws + WS_TAG);

  // converts / transposes / prep
  k_f32_to_bf16<<<2048, 256, 0, stream>>>(enc,    encbf, (LL*BB*H2)/4);
  k_f32_to_bf16<<<512,  256, 0, stream>>>(W_copy, wct,   (DH*H2)/4);
  k_wattn_t<<<dim3(16, 32), 256, 0, stream>>>(W_attn, wa1t, wa2t);
  k_prep<<<32, 256, 0, stream>>>(src, inp, hidden, selw, s2c, emb, mask,
                                 xbf, genbf, h0pbf, h1pbf, scores, selp);

  // h-part: hpf[b][n] = b_attn[n] + h_top @ Wa1
  k_mfma<<<8, 256, 0, stream>>>(h1pbf, 1024, 32, wa1t, 1024, 1024,
                                b_attn, 0, hpf, 8);
  // FUSED: attention scores + copy proj (A staged once)
  k_mfma2<<<1024, 256, 0, stream>>>(encbf, wa2t, wct, hpf, v_attn, b_copy,
                                    scores, projbf);
  k_softmax_attn<<<32, 256, 0, stream>>>(scores, mask, out + ATTN_OFF);
  k_reads<<<dim3(4, 32), 512, 0, stream>>>(encbf, out + ATTN_OFF, selp, xbf, genbf);

  // LSTM layer 0 gates (split-K=7, 56 chunks -> 8/part)
  k_wgemm<<<dim3(64, 7), 256, 0, stream>>>(W_ih0, xbf, KX, W_hh0, h0pbf, DH,
                                           b_ih0, b_hh0, gpart, 4096, 8);
  k_cell<<<128, 256, 0, stream>>>(gpart, 7, cst, out + HID_OFF, out + C_OFF,
                                  h0nbf, 1024);
  // LSTM layer 1 gates (split-K=8, 32 chunks -> 4/part)
  k_wgemm<<<dim3(64, 8), 256, 0, stream>>>(W_ih1, h0nbf, DH, W_hh1, h1pbf, DH,
                                           b_ih1, b_hh1, gpart, 4096, 4);
  k_cell<<<128, 256, 0, stream>>>(gpart, 8, cst + 32768, out + HID_OFF + 32768,
                                  out + C_OFF + 32768, genbf, 2560);

  // copy scores: proj . h1 (+mask +tag init)
  k_pdot<<<4096, 256, 0, stream>>>(projbf, genbf, mask, src, s2c,
                                   out + CS_OFF, tag);

  // generator -> preds[:, :32000]  (40 chunks)
  k_wgemm<<<dim3(500, 1), 256, 0, stream>>>(W_fc, genbf, KX, nullptr, nullptr, 0,
                                            b_fc, nullptr, out, CPY, 40);
  k_zerotail<<<875, 256, 0, stream>>>(out);

  // scatter (last-wins)
  k_tag_max  <<<64, 256, 0, stream>>>(src, s2c, tag);
  k_tag_write<<<64, 256, 0, stream>>>(src, s2c, tag, out + CS_OFF, out);
}

// Round 7
// 355.038 us; speedup vs baseline: 2.5192x; 1.0669x over previous
//
#include <hip/hip_runtime.h>
#include <stdint.h>

typedef unsigned short u16;
typedef unsigned int   u32;
typedef __attribute__((ext_vector_type(8))) short short8;
typedef __attribute__((ext_vector_type(4))) float f32x4;

#define NEGF (-1.0e10f)

// ---------- sizes ----------
static constexpr int LL = 512, BB = 32, EE = 512, H2 = 1024, DH = 1024;
static constexpr int KX = 2560, OUTD = 32000, CPY = 60000;

// ---------- output offsets (floats) ----------
static constexpr size_t HID_OFF   = 1920000;              // 2*32*1024
static constexpr size_t C_OFF     = HID_OFF + 65536;
static constexpr size_t ATTN_OFF  = C_OFF + 65536;        // 32*512
static constexpr size_t CS_OFF    = ATTN_OFF + 16384;     // 32*510

// ---------- workspace offsets (bytes) ----------
static constexpr size_t WS_ENC    = 0;                     // 16384*1024*2 = 33.5MB
static constexpr size_t WS_WA1T   = 33554432;              // 1024*1024*2
static constexpr size_t WS_WA2T   = 35651584;
static constexpr size_t WS_WCT    = 37748736;
static constexpr size_t WS_HPF    = 39845888;              // 32*1024*4
static constexpr size_t WS_SCORES = 39976960;              // 32*512*4
static constexpr size_t WS_SELP   = 40108032;
static constexpr size_t WS_XBF    = 40173568;              // 32*2560*2
static constexpr size_t WS_GENBF  = 40337408;              // 32*2560*2
static constexpr size_t WS_H0PBF  = 40501248;              // 32*1024*2
static constexpr size_t WS_H1PBF  = 40566784;              // 32*1024*2
static constexpr size_t WS_H0NBF  = 40632320;              // 32*1024*2
static constexpr size_t WS_PROJ   = 50331648;              // 16384*1024*2 = 33.5MB
static constexpr size_t WS_TOTAL  = WS_PROJ + 33554432;
// aliased (stream-order safe):
static constexpr size_t WS_GPART  = WS_WA1T;               // 8*32*4096*4 = 4MB (wa1t+wa2t dead after k_mfma2)
static constexpr size_t WS_TAG    = WS_ENC;                // 32*60000*4 (encbf dead after k_reads)

// ---------- helpers ----------
__device__ __forceinline__ u16 f2bf(float x){
  u32 u = __builtin_bit_cast(u32, x);
  u32 r = (u + 0x7FFFu + ((u >> 16) & 1u)) >> 16;
  return (u16)r;
}
__device__ __forceinline__ float bf2f(u16 h){
  u32 u = ((u32)h) << 16; return __builtin_bit_cast(float, u);
}
__device__ __forceinline__ float fsig(float x){ return 1.f/(1.f + __expf(-x)); }
__device__ __forceinline__ float ftanh(float x){
  float e = __expf(2.f*x);
  return 1.f - 2.f/(e + 1.f);
}

#define GLDS16(gp, lp) __builtin_amdgcn_global_load_lds( \
    (__attribute__((address_space(1))) void*)(gp), \
    (__attribute__((address_space(3))) void*)(lp), 16, 0, 0)

// ---------- merged prologue: enc->bf16, Wcopy->bf16, Wattn transpose, prep, tail-zero ----------
// All five sub-tasks are mutually independent; dispatched by blockIdx range.
__global__ void k_pre(const float* __restrict__ enc, u16* __restrict__ encbf,
                      const float* __restrict__ W_copy, u16* __restrict__ wct,
                      const float* __restrict__ W_attn, u16* __restrict__ wa1t, u16* __restrict__ wa2t,
                      const int* __restrict__ src, const int* __restrict__ inp,
                      const float* __restrict__ hidden, const float* __restrict__ selw,
                      const int* __restrict__ s2c, const float* __restrict__ emb,
                      const int* __restrict__ mask,
                      u16* __restrict__ xbf, u16* __restrict__ genbf,
                      u16* __restrict__ h0pbf, u16* __restrict__ h1pbf,
                      float* __restrict__ scores, float* __restrict__ selp,
                      float* __restrict__ preds)
{
  __shared__ float Tt[64*65];
  __shared__ float red[256];
  int bid = blockIdx.x, t = threadIdx.x;

  if (bid < 1024){                       // enc f32 -> bf16 (grid-stride)
    int n4 = (LL*BB*H2)/4;
    for (int i = bid*256 + t; i < n4; i += 1024*256){
      float4 v = ((const float4*)enc)[i];
      u32 lo = (u32)f2bf(v.x) | ((u32)f2bf(v.y) << 16);
      u32 hi = (u32)f2bf(v.z) | ((u32)f2bf(v.w) << 16);
      ((uint2*)encbf)[i] = make_uint2(lo, hi);
    }
  } else if (bid < 1152){                // W_copy f32 -> bf16
    int i = (bid - 1024)*256 + t;
    int n4 = (DH*H2)/4;
    for (; i < n4; i += 128*256){
      float4 v = ((const float4*)W_copy)[i];
      u32 lo = (u32)f2bf(v.x) | ((u32)f2bf(v.y) << 16);
      u32 hi = (u32)f2bf(v.z) | ((u32)f2bf(v.w) << 16);
      ((uint2*)wct)[i] = make_uint2(lo, hi);
    }
  } else if (bid < 1664){                // W_attn transpose -> wa1t/wa2t
    int idx = bid - 1152;
    int n0 = (idx & 15)*64, k0 = (idx >> 4)*64;
    int nn = t & 63, kq = t >> 6;
    for (int kk = kq; kk < 64; kk += 4)
      Tt[kk*65 + nn] = W_attn[(size_t)(k0+kk)*1024 + n0 + nn];
    __syncthreads();
    u16* dst = (k0 < 1024) ? wa1t : wa2t;
    int kbase = (k0 < 1024) ? k0 : (k0 - 1024);
    int kk2 = t & 63, nq = t >> 6;
    for (int nn2 = nq; nn2 < 64; nn2 += 4)
      dst[(size_t)(n0+nn2)*1024 + kbase + kk2] = f2bf(Tt[kk2*65 + nn2]);
  } else if (bid < 1696){                // prep (per-b)
    int b = bid - 1664;
    int ib = inp[b];
    for (int h = t; h < 512; h += 256){
      u16 e = f2bf(emb[(size_t)ib*512 + h]);
      xbf[b*2560 + h] = e;               // x = [emb, att, sel]
      genbf[b*2560 + 2048 + h] = e;      // gen = [h1, att, emb]
    }
    for (int k = t; k < 1024; k += 256){
      h0pbf[b*1024 + k] = f2bf(hidden[b*1024 + k]);
      h1pbf[b*1024 + k] = f2bf(hidden[32768 + b*1024 + k]);
    }
    for (int l = t; l < 512; l += 256)
      scores[b*512 + l] = 0.f;
    float lg[2];
    #pragma unroll
    for (int i = 0; i < 2; ++i){
      int j = t + i*256;
      lg[i] = NEGF;
      if (j < 510){
        int cs = s2c[src[(j+1)*32 + b]];
        if (cs == ib) lg[i] = selw[b*510 + j];
      }
    }
    red[t] = fmaxf(lg[0], lg[1]); __syncthreads();
    for (int s = 128; s > 0; s >>= 1){ if (t < s) red[t] = fmaxf(red[t], red[t+s]); __syncthreads(); }
    float mx = red[0]; __syncthreads();
    float e0 = (t < 510)     ? __expf(lg[0] - mx) : 0.f;
    float e1 = (t+256 < 510) ? __expf(lg[1] - mx) : 0.f;
    red[t] = e0 + e1; __syncthreads();
    for (int s = 128; s > 0; s >>= 1){ if (t < s) red[t] += red[t+s]; __syncthreads(); }
    float inv = 1.f / red[0];
    #pragma unroll
    for (int i = 0; i < 2; ++i){
      int j = t + i*256;
      if (j < 510){
        float v = ((i == 0) ? e0 : e1) * inv;
        int l = j + 1;
        selp[b*512 + l] = (mask[b*512 + l] != 0) ? v : NEGF;
      }
    }
  } else {                               // preds tail zero [32000,60000)
    int i = (bid - 1696)*256 + t;        // 875 blocks x 256 = 224000 float4
    if (i < 224000){
      int b = i / 7000, tt = i % 7000;
      ((float4*)(preds + (size_t)b*CPY + OUTD))[tt] = make_float4(0.f,0.f,0.f,0.f);
    }
  }
}

// ---------- bf16 MFMA GEMM, 128x128 tile, BK=32, dbuf (hpf only) ----------
__launch_bounds__(256)
__global__ void k_mfma(const u16* __restrict__ A, int lda, int Mvalid,
                       const u16* __restrict__ Bmat, int ldb, int K,
                       const float* __restrict__ preadd, int spa,
                       float* __restrict__ outstore, int NT)
{
  __shared__ u16 As[2][128*32];
  __shared__ u16 Bs[2][128*32];
  int wg = blockIdx.x;
  int mt = wg / NT, nt = wg % NT;
  int m0 = mt * 128, n0 = nt * 128;
  int tid = threadIdx.x, lane = tid & 63, wid = tid >> 6;
  int wm = wid >> 1, wn = wid & 1;

  f32x4 acc[4][4];
  #pragma unroll
  for (int i = 0; i < 4; ++i)
    #pragma unroll
    for (int j = 0; j < 4; ++j)
      acc[i][j] = (f32x4){0.f, 0.f, 0.f, 0.f};

  int r0 = tid >> 2,          s0 = tid & 3;
  int r1 = (tid + 256) >> 2;
  int xv0 = (r0 ^ (r0 >> 2)) & 3, xv1 = (r1 ^ (r1 >> 2)) & 3;
  int sc0 = (s0 ^ xv0) << 3,      sc1 = (s0 ^ xv1) << 3;
  int raA0 = m0 + r0; if (raA0 >= Mvalid) raA0 = Mvalid - 1;
  int raA1 = m0 + r1; if (raA1 >= Mvalid) raA1 = Mvalid - 1;
  int rbB0 = n0 + r0, rbB1 = n0 + r1;

  auto stage = [&](int k0, u16* asb, u16* bsb){
    GLDS16(A    + (size_t)raA0*lda + k0 + sc0, (char*)asb + tid*16);
    GLDS16(A    + (size_t)raA1*lda + k0 + sc1, (char*)asb + (tid+256)*16);
    GLDS16(Bmat + (size_t)rbB0*ldb + k0 + sc0, (char*)bsb + tid*16);
    GLDS16(Bmat + (size_t)rbB1*ldb + k0 + sc1, (char*)bsb + (tid+256)*16);
  };

  int KT = K >> 5;
  stage(0, As[0], Bs[0]);
  for (int kt = 0; kt < KT; ++kt){
    __syncthreads();
    if (kt + 1 < KT) stage((kt+1) << 5, As[(kt+1) & 1], Bs[(kt+1) & 1]);
    const char* ap = (const char*)As[kt & 1];
    const char* bp = (const char*)Bs[kt & 1];
    short8 af[4], bfr[4];
    #pragma unroll
    for (int mi = 0; mi < 4; ++mi){
      int rr = wm*64 + mi*16 + (lane & 15);
      int xv = (rr ^ (rr >> 2)) & 3;
      af[mi] = *(const short8*)(ap + rr*64 + (((lane >> 4) ^ xv) << 4));
    }
    #pragma unroll
    for (int nj = 0; nj < 4; ++nj){
      int rr = wn*64 + nj*16 + (lane & 15);
      int xv = (rr ^ (rr >> 2)) & 3;
      bfr[nj] = *(const short8*)(bp + rr*64 + (((lane >> 4) ^ xv) << 4));
    }
    #pragma unroll
    for (int mi = 0; mi < 4; ++mi)
      #pragma unroll
      for (int nj = 0; nj < 4; ++nj)
        acc[mi][nj] = __builtin_amdgcn_mfma_f32_16x16x32_bf16(af[mi], bfr[nj], acc[mi][nj], 0, 0, 0);
  }

  int g = lane >> 4, cn = lane & 15;
  int Nld = NT * 128;
  #pragma unroll
  for (int mi = 0; mi < 4; ++mi)
    #pragma unroll
    for (int rr2 = 0; rr2 < 4; ++rr2){
      int row = m0 + wm*64 + mi*16 + g*4 + rr2;
      if (row < Mvalid){
        #pragma unroll
        for (int nj = 0; nj < 4; ++nj){
          int n = n0 + wn*64 + nj*16 + cn;
          outstore[(size_t)row*Nld + n] = acc[mi][nj][rr2] + preadd[(size_t)(row & 31)*spa + n];
        }
      }
    }
}

// ---------- FUSED dual-B enc GEMM, counted-vmcnt depth-2 pipeline ----------
// Triple-buffered (3 x 24KB). Per phase: s_waitcnt vmcnt(6) certifies stage(kt)
// landed (stage(kt+1)'s 6 GLDS stay in flight) -> raw s_barrier -> issue
// stage(kt+2). No vmcnt(0) drain in the loop (T4). Loop body contains exactly
// 6 GLDS per wave and no other VMEM, so the count is exact by construction.
__launch_bounds__(256, 2)
__global__ void k_mfma2(const u16* __restrict__ A, const u16* __restrict__ B1,
                        const u16* __restrict__ B2, const float* __restrict__ hpf,
                        const float* __restrict__ vattn, const float* __restrict__ bcopy,
                        float* __restrict__ scores, u16* __restrict__ projbf)
{
  __shared__ u16 As [3][128*32];
  __shared__ u16 B1s[3][128*32];
  __shared__ u16 B2s[3][128*32];
  const int lda = 1024;
  int nwg = gridDim.x, bid = blockIdx.x;
  int q = nwg >> 3, r = nwg & 7, xc = bid & 7, ix = bid >> 3;
  int wg = (xc < r ? xc*(q+1) : r*(q+1) + (xc - r)*q) + ix;   // bijective XCD swizzle
  int mt = wg >> 3, nt = wg & 7;                              // NT = 8
  int m0 = mt * 128, n0 = nt * 128;
  int tid = threadIdx.x, lane = tid & 63, wid = tid >> 6;
  int wm = wid >> 1, wn = wid & 1;

  f32x4 acc1[4][4], acc2[4][4];
  #pragma unroll
  for (int i = 0; i < 4; ++i)
    #pragma unroll
    for (int j = 0; j < 4; ++j){
      acc1[i][j] = (f32x4){0.f,0.f,0.f,0.f};
      acc2[i][j] = (f32x4){0.f,0.f,0.f,0.f};
    }

  int r0 = tid >> 2,          s0 = tid & 3;
  int r1 = (tid + 256) >> 2;
  int xv0 = (r0 ^ (r0 >> 2)) & 3, xv1 = (r1 ^ (r1 >> 2)) & 3;
  int sc0 = (s0 ^ xv0) << 3,      sc1 = (s0 ^ xv1) << 3;
  size_t a0 = (size_t)(m0 + r0)*lda, a1 = (size_t)(m0 + r1)*lda;
  size_t b0 = (size_t)(n0 + r0)*lda, b1o = (size_t)(n0 + r1)*lda;

  auto stage = [&](int kt, int buf){
    int k0 = kt << 5;
    GLDS16(A  + a0  + k0 + sc0, (char*)As [buf] + tid*16);
    GLDS16(A  + a1  + k0 + sc1, (char*)As [buf] + (tid+256)*16);
    GLDS16(B1 + b0  + k0 + sc0, (char*)B1s[buf] + tid*16);
    GLDS16(B1 + b1o + k0 + sc1, (char*)B1s[buf] + (tid+256)*16);
    GLDS16(B2 + b0  + k0 + sc0, (char*)B2s[buf] + tid*16);
    GLDS16(B2 + b1o + k0 + sc1, (char*)B2s[buf] + (tid+256)*16);
  };

  stage(0, 0);
  stage(1, 1);
  int cur = 0, pf = 2;
  #pragma unroll 1
  for (int kt = 0; kt < 32; ++kt){
    if (kt < 31) asm volatile("s_waitcnt vmcnt(6)" ::: "memory");
    else         asm volatile("s_waitcnt vmcnt(0)" ::: "memory");
    __builtin_amdgcn_s_barrier();
    if (kt + 2 < 32) stage(kt + 2, pf);
    const char* ap  = (const char*)As [cur];
    const char* b1p = (const char*)B1s[cur];
    const char* b2p = (const char*)B2s[cur];
    short8 af[4], bfr[4];
    #pragma unroll
    for (int mi = 0; mi < 4; ++mi){
      int rr = wm*64 + mi*16 + (lane & 15);
      int xv = (rr ^ (rr >> 2)) & 3;
      af[mi] = *(const short8*)(ap + rr*64 + (((lane >> 4) ^ xv) << 4));
    }
    #pragma unroll
    for (int nj = 0; nj < 4; ++nj){
      int rr = wn*64 + nj*16 + (lane & 15);
      int xv = (rr ^ (rr >> 2)) & 3;
      bfr[nj] = *(const short8*)(b1p + rr*64 + (((lane >> 4) ^ xv) << 4));
    }
    #pragma unroll
    for (int mi = 0; mi < 4; ++mi)
      #pragma unroll
      for (int nj = 0; nj < 4; ++nj)
        acc1[mi][nj] = __builtin_amdgcn_mfma_f32_16x16x32_bf16(af[mi], bfr[nj], acc1[mi][nj], 0, 0, 0);
    #pragma unroll
    for (int nj = 0; nj < 4; ++nj){
      int rr = wn*64 + nj*16 + (lane & 15);
      int xv = (rr ^ (rr >> 2)) & 3;
      bfr[nj] = *(const short8*)(b2p + rr*64 + (((lane >> 4) ^ xv) << 4));
    }
    #pragma unroll
    for (int mi = 0; mi < 4; ++mi)
      #pragma unroll
      for (int nj = 0; nj < 4; ++nj)
        acc2[mi][nj] = __builtin_amdgcn_mfma_f32_16x16x32_bf16(af[mi], bfr[nj], acc2[mi][nj], 0, 0, 0);
    cur = (cur == 2) ? 0 : cur + 1;
    pf  = (pf  == 2) ? 0 : pf  + 1;
  }

  int g = lane >> 4, cn = lane & 15;
  // B1 epilogue: attention score dot
  #pragma unroll
  for (int mi = 0; mi < 4; ++mi)
    #pragma unroll
    for (int rr2 = 0; rr2 < 4; ++rr2){
      int row = m0 + wm*64 + mi*16 + g*4 + rr2;
      int bb = row & 31;
      float part = 0.f;
      #pragma unroll
      for (int nj = 0; nj < 4; ++nj){
        int n = n0 + wn*64 + nj*16 + cn;
        float tv = ftanh(acc1[mi][nj][rr2] + hpf[(size_t)bb*1024 + n]);
        part = fmaf(tv, vattn[n], part);
      }
      part += __shfl_xor(part, 1);
      part += __shfl_xor(part, 2);
      part += __shfl_xor(part, 4);
      part += __shfl_xor(part, 8);
      if (cn == 0) atomicAdd(&scores[(size_t)bb*512 + (row >> 5)], part);
    }
  // B2 epilogue: proj store (bf16)
  #pragma unroll
  for (int mi = 0; mi < 4; ++mi)
    #pragma unroll
    for (int rr2 = 0; rr2 < 4; ++rr2){
      int row = m0 + wm*64 + mi*16 + g*4 + rr2;
      #pragma unroll
      for (int nj = 0; nj < 4; ++nj){
        int n = n0 + wn*64 + nj*16 + cn;
        projbf[(size_t)row*1024 + n] = f2bf(ftanh(acc2[mi][nj][rr2] + bcopy[n]));
      }
    }
}

// ---------- attention softmax over L per b ----------
__global__ void k_softmax_attn(const float* __restrict__ scores, const int* __restrict__ mask,
                               float* __restrict__ attnw){
  int b = blockIdx.x, t = threadIdx.x;
  __shared__ float red[256];
  float v0 = scores[b*512 + t];
  float v1 = scores[b*512 + 256 + t];
  if (mask[b*512 + t] == 0) v0 = NEGF;
  if (mask[b*512 + 256 + t] == 0) v1 = NEGF;
  red[t] = fmaxf(v0, v1); __syncthreads();
  for (int s = 128; s > 0; s >>= 1){ if (t < s) red[t] = fmaxf(red[t], red[t+s]); __syncthreads(); }
  float mx = red[0]; __syncthreads();
  float e0 = __expf(v0 - mx), e1 = __expf(v1 - mx);
  red[t] = e0 + e1; __syncthreads();
  for (int s = 128; s > 0; s >>= 1){ if (t < s) red[t] += red[t+s]; __syncthreads(); }
  float inv = 1.f / red[0];
  attnw[b*512 + t] = e0 * inv;
  attnw[b*512 + 256 + t] = e1 * inv;
}

// ---------- attentive & selective reads (2-way l-split, 512 thr) ----------
__global__ void k_reads(const u16* __restrict__ encbf, const float* __restrict__ attnw,
                        const float* __restrict__ selp,
                        u16* __restrict__ xbf, u16* __restrict__ genbf){
  int b = blockIdx.y;
  int tid = threadIdx.x;
  int h = blockIdx.x*256 + (tid & 255);
  int lh = tid >> 8;
  float aa = 0.f, as = 0.f;
  int l0 = lh*256, l1 = l0 + 256;
  #pragma unroll 4
  for (int l = l0; l < l1; ++l){
    float e = bf2f(encbf[((size_t)l*32 + b)*1024 + h]);
    aa = fmaf(attnw[b*512 + l], e, aa);
    if (l >= 1 && l < 511) as = fmaf(selp[b*512 + l], e, as);
  }
  __shared__ float red[512][2];
  red[tid][0] = aa; red[tid][1] = as;
  __syncthreads();
  if (tid < 256){
    aa = red[tid][0] + red[tid+256][0];
    as = red[tid][1] + red[tid+256][1];
    u16 ab = f2bf(aa);
    xbf[b*2560 + 512 + h]    = ab;
    xbf[b*2560 + 1536 + h]   = f2bf(as);
    genbf[b*2560 + 1024 + h] = ab;
  }
}

// ---------- fused-convert MFMA GEMM: out[b][o] = bias + sum_k W[o][k]*x[b][k] ----------
__launch_bounds__(256)
__global__ void k_wgemm(const float* __restrict__ W1, const u16* __restrict__ xb1, int K1,
                        const float* __restrict__ W2, const u16* __restrict__ xb2, int K2,
                        const float* __restrict__ bias1, const float* __restrict__ bias2,
                        float* __restrict__ outB, int ldo, int cps)
{
  __shared__ u16 As[64*64];      // 8KB, rows of 128B, (row&7) xor-swizzled
  __shared__ u16 Bs[2][32*64];   // 4KB each
  const int tid = threadIdx.x, lane = tid & 63, w = tid >> 6;
  const int o0 = blockIdx.x * 64;
  const int c1 = K1 >> 6;
  const int c0 = blockIdx.y * cps;

  f32x4 acc[2];
  acc[0] = (f32x4){0.f,0.f,0.f,0.f};
  acc[1] = (f32x4){0.f,0.f,0.f,0.f};

  const int ar = tid >> 2, akq = (tid & 3) * 16;
  const int aswz = (ar & 7) << 4;
  const int brow = tid >> 3, pslot = tid & 7;
  const int lslot = pslot ^ (brow & 7);

  float4 aA[4], aB[4];

  auto aload = [&](int c, float4* dst){
    const float* Wp; int Kp, kc;
    if (c < c1){ Wp = W1; Kp = K1; kc = c << 6; }
    else       { Wp = W2; Kp = K2; kc = (c - c1) << 6; }
    const float4* p = (const float4*)(Wp + (size_t)(o0 + ar)*Kp + kc + akq);
    dst[0] = p[0]; dst[1] = p[1]; dst[2] = p[2]; dst[3] = p[3];
  };
  auto bstage = [&](int c, u16* bsb){
    const u16* xp; int Kp, kc;
    if (c < c1){ xp = xb1; Kp = K1; kc = c << 6; }
    else       { xp = xb2; Kp = K2; kc = (c - c1) << 6; }
    GLDS16(xp + (size_t)brow*Kp + kc + lslot*8, (char*)bsb + tid*16);
  };

  auto body = [&](int c, float4* cur, float4* nxt, const u16* bsCur, u16* bsNxt, bool more){
    __syncthreads();
    if (more){ aload(c + 1, nxt); bstage(c + 1, bsNxt); }
    u32 p0 = (u32)f2bf(cur[0].x) | ((u32)f2bf(cur[0].y) << 16);
    u32 p1 = (u32)f2bf(cur[0].z) | ((u32)f2bf(cur[0].w) << 16);
    u32 p2 = (u32)f2bf(cur[1].x) | ((u32)f2bf(cur[1].y) << 16);
    u32 p3 = (u32)f2bf(cur[1].z) | ((u32)f2bf(cur[1].w) << 16);
    u32 p4 = (u32)f2bf(cur[2].x) | ((u32)f2bf(cur[2].y) << 16);
    u32 p5 = (u32)f2bf(cur[2].z) | ((u32)f2bf(cur[2].w) << 16);
    u32 p6 = (u32)f2bf(cur[3].x) | ((u32)f2bf(cur[3].y) << 16);
    u32 p7 = (u32)f2bf(cur[3].z) | ((u32)f2bf(cur[3].w) << 16);
    char* rowp = (char*)As + ar*128;
    *(uint4*)(rowp + ((akq*2)      ^ aswz)) = make_uint4(p0,p1,p2,p3);
    *(uint4*)(rowp + ((akq*2 + 16) ^ aswz)) = make_uint4(p4,p5,p6,p7);
    asm volatile("s_waitcnt lgkmcnt(0)" ::: "memory");
    __builtin_amdgcn_s_barrier();
    #pragma unroll
    for (int kk = 0; kk < 2; ++kk){
      int rrA = w*16 + (lane & 15);
      int kb  = kk*64 + ((lane >> 4) << 4);
      short8 af = *(const short8*)((const char*)As + rrA*128 + (kb ^ ((rrA & 7) << 4)));
      #pragma unroll
      for (int nj = 0; nj < 2; ++nj){
        int rrB = nj*16 + (lane & 15);
        short8 bfv = *(const short8*)((const char*)bsCur + rrB*128 + (kb ^ ((rrB & 7) << 4)));
        acc[nj] = __builtin_amdgcn_mfma_f32_16x16x32_bf16(af, bfv, acc[nj], 0, 0, 0);
      }
    }
  };

  aload(c0, aA); bstage(c0, Bs[0]);
  for (int li = 0; li < cps; li += 2){          // cps even
    body(c0 + li,     aA, aB, Bs[0], Bs[1], true);
    body(c0 + li + 1, aB, aA, Bs[1], Bs[0], (li + 2) < cps);
  }

  int g = lane >> 4, cn = lane & 15;
  int ob = o0 + w*16 + g*4;
  float* outP = outB + (size_t)blockIdx.y * 32 * (size_t)ldo;
  float4 badd = make_float4(0.f,0.f,0.f,0.f);
  if (blockIdx.y == 0){
    if (bias1){ float4 t = *(const float4*)(bias1 + ob);
      badd.x += t.x; badd.y += t.y; badd.z += t.z; badd.w += t.w; }
    if (bias2){ float4 t = *(const float4*)(bias2 + ob);
      badd.x += t.x; badd.y += t.y; badd.z += t.z; badd.w += t.w; }
  }
  #pragma unroll
  for (int nj = 0; nj < 2; ++nj){
    int bcol = nj*16 + cn;
    float4 v = make_float4(acc[nj][0] + badd.x, acc[nj][1] + badd.y,
                           acc[nj][2] + badd.z, acc[nj][3] + badd.w);
    *(float4*)(outP + (size_t)bcol*ldo + ob) = v;
  }
}

// ---------- LSTM cell, fused nparts split-K reduce ----------
__global__ void k_cell(const float* __restrict__ gpart, int nparts,
                       const float* __restrict__ c_in,
                       float* __restrict__ h_out, float* __restrict__ c_out,
                       u16* __restrict__ hbf, int hld){
  int idx = blockIdx.x*256 + threadIdx.x;
  int b = idx >> 10, j = idx & 1023;
  float gi = 0.f, gf = 0.f, gg = 0.f, go = 0.f;
  for (int p = 0; p < nparts; ++p){
    const float* gb = gpart + (size_t)p*131072 + (size_t)b*4096;
    gi += gb[j];
    gf += gb[1024 + j];
    gg += gb[2048 + j];
    go += gb[3072 + j];
  }
  float cv = c_in[b*1024 + j];
  float cnv = fsig(gf)*cv + fsig(gi)*ftanh(gg);
  float hn  = fsig(go)*ftanh(cnv);
  c_out[b*1024 + j] = cnv;
  h_out[b*1024 + j] = hn;
  hbf[(size_t)b*hld + j] = f2bf(hn);
}

// ---------- proj . h1 dot -> copy scores (+mask, +tag init) ----------
__global__ void k_pdot(const u16* __restrict__ projbf, const u16* __restrict__ genbf,
                       const int* __restrict__ mask, const int* __restrict__ src,
                       const int* __restrict__ s2c,
                       float* __restrict__ cs_out, int* __restrict__ tag)
{
  int tid = threadIdx.x, lane = tid & 63, w = tid >> 6;
  int row = blockIdx.x*4 + w;                 // 4096 blocks x 4 waves
  int l = row >> 5, b = row & 31;
  const u16* pr = projbf + (size_t)row*1024 + lane*16;
  const u16* hr = genbf  + (size_t)b*2560 + lane*16;
  short8 p0 = *(const short8*)pr,     p1 = *(const short8*)(pr + 8);
  short8 h0 = *(const short8*)hr,     h1 = *(const short8*)(hr + 8);
  float s = 0.f;
  #pragma unroll
  for (int i = 0; i < 8; ++i) s = fmaf(bf2f((u16)p0[i]), bf2f((u16)h0[i]), s);
  #pragma unroll
  for (int i = 0; i < 8; ++i) s = fmaf(bf2f((u16)p1[i]), bf2f((u16)h1[i]), s);
  s += __shfl_xor(s, 1);  s += __shfl_xor(s, 2);  s += __shfl_xor(s, 4);
  s += __shfl_xor(s, 8);  s += __shfl_xor(s, 16); s += __shfl_xor(s, 32);
  if (lane == 0 && l >= 1 && l <= 510){
    int j = l - 1;
    cs_out[b*510 + j] = (mask[b*512 + l] != 0) ? s : NEGF;
    tag[(size_t)b*CPY + s2c[src[l*32 + b]]] = -1;
  }
}

// ---------- scatter passes ----------
__global__ void k_tag_max(const int* __restrict__ src, const int* __restrict__ s2c,
                          int* __restrict__ tag){
  int i = blockIdx.x*256 + threadIdx.x;
  if (i < 16320){
    int b = i / 510, j = i % 510;
    atomicMax(&tag[(size_t)b*CPY + s2c[src[(j+1)*32 + b]]], j);
  }
}
__global__ void k_tag_write(const int* __restrict__ src, const int* __restrict__ s2c,
                            const int* __restrict__ tag, const float* __restrict__ cs,
                            float* __restrict__ preds){
  int i = blockIdx.x*256 + threadIdx.x;
  if (i < 16320){
    int b = i / 510, j = i % 510;
    int idx = s2c[src[(j+1)*32 + b]];
    if (tag[(size_t)b*CPY + idx] == j)
      preds[(size_t)b*CPY + idx] = cs[b*510 + j];
  }
}

extern "C" void kernel_launch(void* const* d_in, const int* in_sizes, int n_in,
                              void* d_out, int out_size, void* d_ws, size_t ws_size,
                              hipStream_t stream){
  const int*   src    = (const int*)  d_in[0];
  const int*   inp    = (const int*)  d_in[1];
  const float* hidden = (const float*)d_in[2];
  const float* cst    = (const float*)d_in[3];
  const float* enc    = (const float*)d_in[4];
  const int*   mask   = (const int*)  d_in[5];
  const float* selw   = (const float*)d_in[6];
  const int*   s2c    = (const int*)  d_in[7];
  const float* emb    = (const float*)d_in[8];
  const float* W_attn = (const float*)d_in[9];
  const float* b_attn = (const float*)d_in[10];
  const float* v_attn = (const float*)d_in[11];
  const float* W_ih0  = (const float*)d_in[12];
  const float* W_hh0  = (const float*)d_in[13];
  const float* b_ih0  = (const float*)d_in[14];
  const float* b_hh0  = (const float*)d_in[15];
  const float* W_ih1  = (const float*)d_in[16];
  const float* W_hh1  = (const float*)d_in[17];
  const float* b_ih1  = (const float*)d_in[18];
  const float* b_hh1  = (const float*)d_in[19];
  const float* W_fc   = (const float*)d_in[20];
  const float* b_fc   = (const float*)d_in[21];
  const float* W_copy = (const float*)d_in[22];
  const float* b_copy = (const float*)d_in[23];

  if (ws_size < WS_TOTAL) return;

  float* out = (float*)d_out;
  char*  ws  = (char*)d_ws;
  u16*   encbf  = (u16*)  (ws + WS_ENC);
  u16*   wa1t   = (u16*)  (ws + WS_WA1T);
  u16*   wa2t   = (u16*)  (ws + WS_WA2T);
  u16*   wct    = (u16*)  (ws + WS_WCT);
  float* hpf    = (float*)(ws + WS_HPF);
  float* scores = (float*)(ws + WS_SCORES);
  float* selp   = (float*)(ws + WS_SELP);
  u16*   xbf    = (u16*)  (ws + WS_XBF);
  u16*   genbf  = (u16*)  (ws + WS_GENBF);
  u16*   h0pbf  = (u16*)  (ws + WS_H0PBF);
  u16*   h1pbf  = (u16*)  (ws + WS_H1PBF);
  u16*   h0nbf  = (u16*)  (ws + WS_H0NBF);
  u16*   projbf = (u16*)  (ws + WS_PROJ);
  float* gpart  = (float*)(ws + WS_GPART);
  int*   tag    = (int*)  (ws + WS_TAG);

  // merged prologue: enc->bf16 | Wcopy->bf16 | Wattn transpose | prep | tail-zero
  k_pre<<<2571, 256, 0, stream>>>(enc, encbf, W_copy, wct, W_attn, wa1t, wa2t,
                                  src, inp, hidden, selw, s2c, emb, mask,
                                  xbf, genbf, h0pbf, h1pbf, scores, selp, out);

  // h-part: hpf[b][n] = b_attn[n] + h_top @ Wa1
  k_mfma<<<8, 256, 0, stream>>>(h1pbf, 1024, 32, wa1t, 1024, 1024,
                                b_attn, 0, hpf, 8);
  // FUSED: attention scores + copy proj (A staged once, counted-vmcnt pipeline)
  k_mfma2<<<1024, 256, 0, stream>>>(encbf, wa2t, wct, hpf, v_attn, b_copy,
                                    scores, projbf);
  k_softmax_attn<<<32, 256, 0, stream>>>(scores, mask, out + ATTN_OFF);
  k_reads<<<dim3(4, 32), 512, 0, stream>>>(encbf, out + ATTN_OFF, selp, xbf, genbf);

  // LSTM layer 0 gates (split-K=7, 56 chunks -> 8/part)
  k_wgemm<<<dim3(64, 7), 256, 0, stream>>>(W_ih0, xbf, KX, W_hh0, h0pbf, DH,
                                           b_ih0, b_hh0, gpart, 4096, 8);
  k_cell<<<128, 256, 0, stream>>>(gpart, 7, cst, out + HID_OFF, out + C_OFF,
                                  h0nbf, 1024);
  // LSTM layer 1 gates (split-K=8, 32 chunks -> 4/part)
  k_wgemm<<<dim3(64, 8), 256, 0, stream>>>(W_ih1, h0nbf, DH, W_hh1, h1pbf, DH,
                                           b_ih1, b_hh1, gpart, 4096, 4);
  k_cell<<<128, 256, 0, stream>>>(gpart, 8, cst + 32768, out + HID_OFF + 32768,
                                  out + C_OFF + 32768, genbf, 2560);

  // copy scores: proj . h1 (+mask +tag init)
  k_pdot<<<4096, 256, 0, stream>>>(projbf, genbf, mask, src, s2c,
                                   out + CS_OFF, tag);

  // generator -> preds[:, :32000]  (40 chunks)
  k_wgemm<<<dim3(500, 1), 256, 0, stream>>>(W_fc, genbf, KX, nullptr, nullptr, 0,
                                            b_fc, nullptr, out, CPY, 40);

  // scatter (last-wins)
  k_tag_max  <<<64, 256, 0, stream>>>(src, s2c, tag);
  k_tag_write<<<64, 256, 0, stream>>>(src, s2c, tag, out + CS_OFF, out);
}